// Round 4
// baseline (817.993 us; speedup 1.0000x reference)
//
#include <hip/hip_runtime.h>
#include <cstdint>
#include <cstddef>

#define NB   4096
#define OBS  512
#define NACT 64
#define NT   10
#define NE   16
#define DREP 1024
#define DH   1024
#define DK   512
#define SLD  (OBS + NT)    // 522, state row length
#define XK   (OBS + NACT)  // 576

typedef short s8v __attribute__((ext_vector_type(8)));  // 8 bf16 in 4 VGPRs
typedef float f4v __attribute__((ext_vector_type(4)));

__device__ __forceinline__ unsigned short f2bf(float f) {
  union { float f; unsigned int u; } v; v.f = f;
  unsigned int u = v.u;
  unsigned int r = (u + 0x7FFFu + ((u >> 16) & 1u)) >> 16;  // RNE
  return (unsigned short)r;
}
__device__ __forceinline__ float bf2f(unsigned short h) {
  union { unsigned int u; float f; } v; v.u = ((unsigned int)h) << 16;
  return v.f;
}

__device__ __forceinline__ void gload_lds16(const unsigned short* gp, const unsigned short* lp) {
  __builtin_amdgcn_global_load_lds(
      (const __attribute__((address_space(1))) void*)(uintptr_t)gp,
      (__attribute__((address_space(3))) void*)(unsigned int)(uintptr_t)lp,
      16, 0, 0);
}

// ---------------------------------------------------------------------------
// Generic bf16 GEMM: C[M,N] = A[M,K] @ Bt[N,K]^T  (Bt is N-major, K contiguous)
// 3-stage pipelined K-loop, 128x128 tile, 4 waves. Kept for rep-MLP, split-K
// V2 (MODE 3/4) and tower (grids too small for the 256-tile kernel there).
// MODE 0: out = bf16(maybe_relu(C + bias[col]))
// MODE 3 (split-K partial write): P[z][row][col]  = C
// MODE 4 (split-K partial add):   P[z][row][col] += C
// ---------------------------------------------------------------------------
template <int BM, int BN, int MODE, int RELU, int LDA, int LDB, int KK>
__global__ void __launch_bounds__(256)
gemm_k(const unsigned short* __restrict__ A,
       const unsigned short* __restrict__ Bt,
       const float* __restrict__ bias,
       unsigned short* __restrict__ outB, int ldo,
       const float* __restrict__ qk1, const int* __restrict__ task,
       float* __restrict__ logits, int eBase,
       const float* __restrict__ attn, float* __restrict__ cio)
{
  constexpr int FM = BM / 32;   // 16x16 frags per wave (M)
  constexpr int FN = BN / 32;
  constexpr int CA = BM / 64;   // 1KB staging chunks per wave (A)
  constexpr int CB = BN / 64;
  constexpr int NTILES = KK / 32;
  static_assert(NTILES >= 3, "pipeline depth");
  constexpr int LPS = CA + CB;           // loads per stage per wave
  static_assert(LPS < 16, "vmcnt immediate fits in low bits");
  constexpr int WAIT_STAGE = 0xF70 | LPS;  // vmcnt(LPS): prev stage done
  constexpr int WAIT_ALL   = 0xF70;        // vmcnt(0): drain (tail only)

  __shared__ __align__(16) unsigned short As[3][BM * 32];
  __shared__ __align__(16) unsigned short Bs[3][BN * 32];

  const int tid  = threadIdx.x;
  const int wave = tid >> 6;
  const int lane = tid & 63;
  const int wm = wave >> 1, wn = wave & 1;

  const int rowBase = blockIdx.x * BM;
  const int colBase = blockIdx.y * BN;

  if (MODE == 3 || MODE == 4) {
    A   += (size_t)blockIdx.z * KK;    // K-chunk
    Bt  += (size_t)blockIdx.z * KK;
    cio += (size_t)blockIdx.z * NB * DK;
  }

  f4v acc[FM][FN];
#pragma unroll
  for (int m = 0; m < FM; ++m)
#pragma unroll
    for (int n = 0; n < FN; ++n) acc[m][n] = f4v{0.f, 0.f, 0.f, 0.f};

  const int sRow = lane >> 2;                                 // row within 16-row chunk
  const int sSw  = ((lane & 3) ^ ((sRow >> 1) & 3)) * 8;      // swizzled global k-offset

  const unsigned short* ag[CA];
  const unsigned short* bg[CB];
#pragma unroll
  for (int j = 0; j < CA; ++j)
    ag[j] = A + (size_t)(rowBase + (wave * CA + j) * 16 + sRow) * LDA + sSw;
#pragma unroll
  for (int j = 0; j < CB; ++j)
    bg[j] = Bt + (size_t)(colBase + (wave * CB + j) * 16 + sRow) * LDB + sSw;

  const int fr   = lane & 15;
  const int koSw = ((lane >> 4) ^ ((fr >> 1) & 3)) * 8;       // swizzled read slot
  const int aOff = (wm * (BM / 2) + fr) * 32 + koSw;
  const int bOff = (wn * (BN / 2) + fr) * 32 + koSw;

  auto stage = [&](int buf) {
#pragma unroll
    for (int j = 0; j < CA; ++j) { gload_lds16(ag[j], &As[buf][(wave * CA + j) * 512]); ag[j] += 32; }
#pragma unroll
    for (int j = 0; j < CB; ++j) { gload_lds16(bg[j], &Bs[buf][(wave * CB + j) * 512]); bg[j] += 32; }
  };

  auto compute = [&](int buf) {
    s8v av[FM], bv[FN];
#pragma unroll
    for (int m = 0; m < FM; ++m)
      av[m] = *reinterpret_cast<const s8v*>(&As[buf][aOff + m * 512]);
#pragma unroll
    for (int n = 0; n < FN; ++n)
      bv[n] = *reinterpret_cast<const s8v*>(&Bs[buf][bOff + n * 512]);
#pragma unroll
    for (int m = 0; m < FM; ++m)
#pragma unroll
      for (int n = 0; n < FN; ++n)
        acc[m][n] = __builtin_amdgcn_mfma_f32_16x16x32_bf16(av[m], bv[n], acc[m][n], 0, 0, 0);
  };

  stage(0);   // tile 0
  stage(1);   // tile 1

  for (int t = 0; t < NTILES; t += 3) {
    // ---- tile t (buf 0) ----
    if (t + 1 < NTILES) __builtin_amdgcn_s_waitcnt(WAIT_STAGE);
    else                __builtin_amdgcn_s_waitcnt(WAIT_ALL);
    __builtin_amdgcn_s_barrier();
    if (t + 2 < NTILES) stage(2);
    compute(0);
    // ---- tile t+1 (buf 1) ----
    if (t + 1 < NTILES) {
      if (t + 2 < NTILES) __builtin_amdgcn_s_waitcnt(WAIT_STAGE);
      else                __builtin_amdgcn_s_waitcnt(WAIT_ALL);
      __builtin_amdgcn_s_barrier();
      if (t + 3 < NTILES) stage(0);
      compute(1);
    }
    // ---- tile t+2 (buf 2) ----
    if (t + 2 < NTILES) {
      if (t + 3 < NTILES) __builtin_amdgcn_s_waitcnt(WAIT_STAGE);
      else                __builtin_amdgcn_s_waitcnt(WAIT_ALL);
      __builtin_amdgcn_s_barrier();
      if (t + 4 < NTILES) stage(1);
      compute(2);
    }
  }

  // ---------------- epilogue ----------------
  const int cr = (lane >> 4) * 4;  // row base within fragment
  const int cc = lane & 15;        // col within fragment

  int gcn[FN];
  float bcol[FN];
#pragma unroll
  for (int n = 0; n < FN; ++n) {
    gcn[n] = colBase + wn * (BN / 2) + n * 16 + cc;
    bcol[n] = (MODE >= 3) ? 0.f : bias[gcn[n]];
  }

  if (MODE == 0) {
#pragma unroll
    for (int m = 0; m < FM; ++m)
#pragma unroll
      for (int r = 0; r < 4; ++r) {
        int gr = rowBase + wm * (BM / 2) + m * 16 + cr + r;
#pragma unroll
        for (int n = 0; n < FN; ++n) {
          float v = acc[m][n][r] + bcol[n];
          if (RELU) v = fmaxf(v, 0.f);
          outB[(size_t)gr * ldo + gcn[n]] = f2bf(v);
        }
      }
  }

  if (MODE == 3 || MODE == 4) {
#pragma unroll
    for (int m = 0; m < FM; ++m)
#pragma unroll
      for (int r = 0; r < 4; ++r) {
        int gr = rowBase + wm * (BM / 2) + m * 16 + cr + r;
#pragma unroll
        for (int n = 0; n < FN; ++n) {
          float v = acc[m][n][r];
          if (MODE == 4) v += cio[(size_t)gr * DK + gcn[n]];
          cio[(size_t)gr * DK + gcn[n]] = v;
        }
      }
  }
}

// ---------------------------------------------------------------------------
// 256x256-tile, BK=32, 8-wave GEMM, v4: TRI-BUFFERED LDS + counted vmcnt,
// fine phases (m201/m218 discipline).
// R3 post-mortem: all drain-0 / lockstep variants pin at 34-37% MfmaUtil
// (LDS pipe 2300cyc + MFMA 2480cyc run serialized, 6000cyc/tile).  m218: the
// lever is counted vmcnt that NEVER drains mid-loop; m196: fine {reads |
// stage | barrier | 16 MFMA | barrier} phases.  A double buffer cannot give
// both (every LDS half is read in every phase -> no WAR-safe prefetch target
// 2 tiles out -> forced drain-0).  Tri-buffer solves it:
//   tile t reads buf t%3;  tile t+2 stages into buf (t+2)%3 == buf (t-1)%3,
//   whose reads all retired before tile t began (>=1 barrier-generation ago).
// Per tile (BK=32, one k-step): 2 phases:
//   P1: readA(rows rh=0: 4x b128) + readB(4x b128); stage A0,A1(t+2);
//       barrier; 16 MFMA (4m x 4n, independent); barrier.
//   P2: readA(rh=1: 4x b128) [bv reused]; stage B0,B1(t+2); vmcnt(4);
//       barrier; 16 MFMA; barrier.
// vmcnt ledger: at P2's check, outstanding = t+1's 4 stages (from tile t-1)
// + t+2's 4 (this tile); vmcnt(4) retires exactly t+1 (in-order) -> tile t+1
// resident for next phase; t+2 stays in flight.  NEVER 0 mid-loop (tail
// drains once at t=NTK-2).  MFMA execution drains asynchronously past the
// barriers, so phase p+1's ds_reads overlap phase p's matrix work.
// LDS = 3 x (16KB A + 16KB B) = 96KB -> still 1 block/CU.
// Swizzle: 4 chunks/row, chunk c stored at c ^ (row&3); staging pre-swizzles
// the GLOBAL k-offset (gload_lds dest is linear); verified-conflict-free
// pattern (R1-R3: SQ_LDS_BANK_CONFLICT = 0).
// Wave grid 2M x 4N: wave_m=wave>>2 (128 rows), wave_n=wave&3 (64 cols).
// MODE 1 (K-pass): v=relu(C+bk0[e,col]); logits[row,e] += v*qk1[e,task,col]
// MODE 2 (V-pass): out = bf16(attn[row,e] * relu(C + bv0[e,col]))
// ---------------------------------------------------------------------------
template <int MODE, int LDA, int LDB, int KK>
__global__ void __launch_bounds__(512)
gemm256_k(const unsigned short* __restrict__ A,
          const unsigned short* __restrict__ Bt,
          const float* __restrict__ bias,
          unsigned short* __restrict__ outB, int ldo,
          const float* __restrict__ qk1, const int* __restrict__ task,
          float* __restrict__ logits, int eBase,
          const float* __restrict__ attn)
{
  constexpr int NTK = KK / 32;           // 32 K-tiles
  static_assert(NTK >= 4, "pipeline depth");
  constexpr int BUFS = 8192;             // shorts per tile-buffer (128..: 256rows*32k? no: per-array half covers 256 rows? A buf = 256x32x2B = 16KB = 8192 shorts)

  __shared__ __align__(16) unsigned short AsF[3 * BUFS];  // [buf][half*4096 + row*32 + swzchunk*8]
  __shared__ __align__(16) unsigned short BsF[3 * BUFS];

  const int tid  = threadIdx.x;
  const int wave = tid >> 6;
  const int lane = tid & 63;
  const int fr = lane & 15;       // frag row/col index
  const int l4 = lane >> 4;       // k-chunk index 0..3
  const int wave_m = wave >> 2;   // 0..1 -> rows wave_m*128
  const int wave_n = wave & 3;    // 0..3 -> cols wave_n*64

  // ---- XCD-bijective block swizzle (requires nwg % 8 == 0; holds here) ----
  const int gx = gridDim.x, gy = gridDim.y;
  int flat = blockIdx.x + gx * (blockIdx.y + gy * blockIdx.z);
  const int nwg = gx * gy * gridDim.z;
  flat = (flat & 7) * (nwg >> 3) + (flat >> 3);
  const int bx = flat % gx; flat /= gx;
  const int by = flat % gy;
  const int bz = flat / gy;

  const int rowBase = bx * 256;
  const int colBase = by * 256;

  int eg = 0;
  if (MODE == 1) {
    eg = bz;
    Bt   += (size_t)eg * ((size_t)DREP * DH);
    bias += eg * DH;
    qk1  += (size_t)eg * (NT * DH);
  }
  if (MODE == 2) {
    eg = eBase + bz;
    Bt   += (size_t)eg * ((size_t)DREP * DH);
    bias += eg * DH;
    outB += (size_t)bz * DH;   // local slab in Ap
  }

  f4v acc[2][4][4];   // [rh][m4][n4]
#pragma unroll
  for (int i0 = 0; i0 < 2; ++i0)
#pragma unroll
    for (int i1 = 0; i1 < 4; ++i1)
#pragma unroll
      for (int i2 = 0; i2 < 4; ++i2)
        acc[i0][i1][i2] = f4v{0.f, 0.f, 0.f, 0.f};

  // ---- staging: half-tile = 128 rows x 32 k (8KB) = 1 x 16B per thread ----
  // wave covers rows h*128 + wave*16 + (lane>>2); lane&3 = stored chunk.
  // Pre-swizzled global k-offset: logical chunk = (lane&3) ^ (row&3).
  const int sRow = lane >> 2;
  const int sKo  = ((lane & 3) ^ (sRow & 3)) * 8;
  const unsigned short* pA[2];
  const unsigned short* pB[2];
#pragma unroll
  for (int h = 0; h < 2; ++h) {
    const int r = h * 128 + wave * 16 + sRow;
    pA[h] = A  + (size_t)(rowBase + r) * LDA + sKo;
    pB[h] = Bt + (size_t)(colBase + r) * LDB + sKo;
  }

  auto stageA = [&](int bufO, int h) {
    gload_lds16(pA[h], &AsF[bufO + h * 4096 + wave * 512]);
    pA[h] += 32;
  };
  auto stageB = [&](int bufO, int h) {
    gload_lds16(pB[h], &BsF[bufO + h * 4096 + wave * 512]);
    pB[h] += 32;
  };

  // ---- LDS -> fragment read bases (swizzle-aware) ----
  // A: [half=wave_m][row = rh*64 + m4*16 + fr][chunk (l4)^(fr&3)]
  const int swz   = (l4 ^ (fr & 3)) * 8;
  const int aC    = wave_m * 4096 + fr * 32 + swz;
  const int bC    = (wave_n >> 1) * 4096 + ((wave_n & 1) * 64 + fr) * 32 + swz;

  s8v av[4], bv[4];
  auto readA = [&](int aAddr, int rh) {
#pragma unroll
    for (int m4 = 0; m4 < 4; ++m4)
      av[m4] = *reinterpret_cast<const s8v*>(&AsF[aAddr + rh * 2048 + m4 * 512]);
  };
  auto readB = [&](int bAddr) {
#pragma unroll
    for (int n4 = 0; n4 < 4; ++n4)
      bv[n4] = *reinterpret_cast<const s8v*>(&BsF[bAddr + n4 * 512]);
  };

#define MFMA_PH(RH)                                                           \
  do {                                                                        \
    __builtin_amdgcn_s_setprio(1);                                            \
    _Pragma("unroll") for (int m4_ = 0; m4_ < 4; ++m4_)                       \
      _Pragma("unroll") for (int n4_ = 0; n4_ < 4; ++n4_)                     \
        acc[RH][m4_][n4_] = __builtin_amdgcn_mfma_f32_16x16x32_bf16(          \
            av[m4_], bv[n4_], acc[RH][m4_][n4_], 0, 0, 0);                    \
    __builtin_amdgcn_s_setprio(0);                                            \
  } while (0)

  // ---- prologue: stage t0 -> buf0, t1 -> buf1; vmcnt(4): t0 resident ----
  stageA(0, 0); stageA(0, 1); stageB(0, 0); stageB(0, 1);
  stageA(BUFS, 0); stageA(BUFS, 1); stageB(BUFS, 0); stageB(BUFS, 1);
  __builtin_amdgcn_s_waitcnt(0xF74);
  __builtin_amdgcn_s_barrier();

  int bufR = 0;           // buf of tile t
  int bufS = 2 * BUFS;    // buf of tile t+2  == buf of tile t-1 (retired)

  for (int t = 0; t < NTK; ++t) {
    const bool st = (t + 2) < NTK;
    const int aAddr = bufR + aC;
    const int bAddr = bufR + bC;
    // ---- P1: rows rh=0 ----
    readA(aAddr, 0);
    readB(bAddr);
    if (st) { stageA(bufS, 0); stageA(bufS, 1); }
    __builtin_amdgcn_s_barrier();
    MFMA_PH(0);
    __builtin_amdgcn_s_barrier();
    // ---- P2: rows rh=1 (bv reused) ----
    readA(aAddr, 1);
    if (st) { stageB(bufS, 0); stageB(bufS, 1); }
    if (st)               __builtin_amdgcn_s_waitcnt(0xF74);  // vmcnt(4): t+1 in
    else if (t + 1 < NTK) __builtin_amdgcn_s_waitcnt(0xF70);  // tail drain once
    __builtin_amdgcn_s_barrier();
    MFMA_PH(1);
    __builtin_amdgcn_s_barrier();
    bufR = (bufR == 2 * BUFS) ? 0 : bufR + BUFS;
    bufS = (bufS == 2 * BUFS) ? 0 : bufS + BUFS;
  }
#undef MFMA_PH

  // ---------------- epilogue ----------------
  const int cr = l4 * 4;
  const int cc = fr;

  int gcn[4];
  float bcol[4];
#pragma unroll
  for (int n4 = 0; n4 < 4; ++n4) {
    gcn[n4]  = colBase + wave_n * 64 + n4 * 16 + cc;
    bcol[n4] = bias[gcn[n4]];
  }

  if (MODE == 1) {
#pragma unroll
    for (int rh = 0; rh < 2; ++rh)
#pragma unroll
      for (int m4 = 0; m4 < 4; ++m4)
#pragma unroll
        for (int r = 0; r < 4; ++r) {
          const int gr = rowBase + wave_m * 128 + rh * 64 + m4 * 16 + cr + r;
          const float* qrow = qk1 + (size_t)task[gr] * DH;
          float s = 0.f;
#pragma unroll
          for (int n4 = 0; n4 < 4; ++n4) {
            float v = fmaxf(acc[rh][m4][n4][r] + bcol[n4], 0.f);
            s += v * qrow[gcn[n4]];
          }
#pragma unroll
          for (int off = 1; off < 16; off <<= 1) s += __shfl_xor(s, off, 64);
          if (cc == 0) atomicAdd(&logits[gr * NE + eg], s);
        }
  }

  if (MODE == 2) {
#pragma unroll
    for (int rh = 0; rh < 2; ++rh)
#pragma unroll
      for (int m4 = 0; m4 < 4; ++m4)
#pragma unroll
        for (int r = 0; r < 4; ++r) {
          const int gr = rowBase + wave_m * 128 + rh * 64 + m4 * 16 + cr + r;
          const float aw = attn[gr * NE + eg];
#pragma unroll
          for (int n4 = 0; n4 < 4; ++n4) {
            float v = fmaxf(acc[rh][m4][n4][r] + bcol[n4], 0.f) * aw;
            outB[(size_t)gr * ldo + gcn[n4]] = f2bf(v);
          }
        }
  }
}

// ---------------------------------------------------------------------------
// small kernels
// ---------------------------------------------------------------------------
__global__ void task_k(const float* __restrict__ state, int* __restrict__ task) {
  int b = blockIdx.x * blockDim.x + threadIdx.x;
  if (b >= NB) return;
  const float* p = state + (size_t)b * SLD + OBS;
  float best = p[0]; int bi = 0;
  for (int j = 1; j < NT; ++j) { float v = p[j]; if (v > best) { best = v; bi = j; } }
  task[b] = bi;
}

__global__ void buildx_k(const float* __restrict__ state, const float* __restrict__ act,
                         unsigned short* __restrict__ x) {
  int idx = blockIdx.x * blockDim.x + threadIdx.x;
  if (idx >= NB * XK) return;
  int b = idx / XK, j = idx - b * XK;
  float v = (j < OBS) ? state[(size_t)b * SLD + j] : act[(size_t)b * NACT + (j - OBS)];
  x[idx] = f2bf(v);
}

// block t: Qt[t,:] = tanh(emb[t,:]); qb[e,t] = Qt[t,:] . bk1[e,:]
__global__ void prep_emb_k(const float* __restrict__ emb, const float* __restrict__ bk1,
                           float* __restrict__ Qt, float* __restrict__ qb) {
  int t = blockIdx.x;
  __shared__ float qsh[DK];
  for (int k = threadIdx.x; k < DK; k += 256) {
    float v = tanhf(emb[t * DK + k]);
    Qt[t * DK + k] = v;
    qsh[k] = v;
  }
  __syncthreads();
  int wave = threadIdx.x >> 6, lane = threadIdx.x & 63;
  for (int e = wave; e < NE; e += 4) {
    float s = 0.f;
    for (int k = lane; k < DK; k += 64) s += qsh[k] * bk1[e * DK + k];
    for (int off = 1; off < 64; off <<= 1) s += __shfl_xor(s, off, 64);
    if (lane == 0) qb[e * NT + t] = s;
  }
}

// wave per (e,h): qk1[e,t,h] = sum_k Wk1[e,h,k] * Qt[t,k]
__global__ void qk1_k(const float* __restrict__ Wk1, const float* __restrict__ Qt,
                      float* __restrict__ qk1) {
  int w = (blockIdx.x * blockDim.x + threadIdx.x) >> 6;
  int lane = threadIdx.x & 63;
  if (w >= NE * DH) return;
  int e = w >> 10, h = w & (DH - 1);
  const float* wrow = Wk1 + ((size_t)e * DH + h) * DK + lane * 8;
  float wv[8];
#pragma unroll
  for (int j = 0; j < 8; ++j) wv[j] = wrow[j];
#pragma unroll
  for (int t = 0; t < NT; ++t) {
    const float* qrow = Qt + t * DK + lane * 8;
    float s = 0.f;
#pragma unroll
    for (int j = 0; j < 8; ++j) s += wv[j] * qrow[j];
#pragma unroll
    for (int off = 1; off < 64; off <<= 1) s += __shfl_xor(s, off, 64);
    if (lane == 0) qk1[((size_t)e * NT + t) * DH + h] = s;
  }
}

// transpose + fp32->bf16, 64x64 tile, coalesced float4 reads + 16B bf16 writes.
// dst[e*dBS + n*dLd + k] = bf16(src[e*sBS + k*N + n])
__global__ void __launch_bounds__(256)
convT_k(const float* __restrict__ src, unsigned short* __restrict__ dst,
        int N, long sBS, long dBS, int dLd) {
  __shared__ float tile[64][65];
  int e = blockIdx.z;
  int n0 = blockIdx.x * 64, k0 = blockIdx.y * 64;
  src += (size_t)e * sBS + (size_t)k0 * N + n0;
  dst += (size_t)e * dBS + (size_t)n0 * dLd + k0;
  int t = threadIdx.x;
  int c4 = t & 15, kr = t >> 4;            // 16 float4-cols x 16 rows per pass
#pragma unroll
  for (int i = 0; i < 4; ++i) {
    float4 v = *(const float4*)(src + (size_t)(kr + i * 16) * N + c4 * 4);
    tile[kr + i * 16][c4 * 4 + 0] = v.x;
    tile[kr + i * 16][c4 * 4 + 1] = v.y;
    tile[kr + i * 16][c4 * 4 + 2] = v.z;
    tile[kr + i * 16][c4 * 4 + 3] = v.w;
  }
  __syncthreads();
  int sub = t & 7, nl = t >> 3;            // 8 k-chunks x 32 n per pass
#pragma unroll
  for (int pass = 0; pass < 2; ++pass) {
    int n = nl + pass * 32;
    unsigned short v8[8];
#pragma unroll
    for (int j = 0; j < 8; ++j) v8[j] = f2bf(tile[sub * 8 + j][n]);
    *reinterpret_cast<s8v*>(dst + (size_t)n * dLd + sub * 8) =
        *reinterpret_cast<const s8v*>(v8);
  }
}

__global__ void softmax_k(const float* __restrict__ logits, const float* __restrict__ qb,
                          const int* __restrict__ task, float* __restrict__ attn,
                          float* __restrict__ lossOut) {
  int b = blockIdx.x * blockDim.x + threadIdx.x;
  int t = task[b];
  float l[NE];
  float mx = -1e30f;
#pragma unroll
  for (int e = 0; e < NE; ++e) { l[e] = logits[b * NE + e] + qb[e * NT + t]; mx = fmaxf(mx, l[e]); }
  float s = 0.f;
#pragma unroll
  for (int e = 0; e < NE; ++e) { l[e] = expf(l[e] - mx); s += l[e]; }
  float inv = 1.f / s;
  float loss = 0.f;
#pragma unroll
  for (int e = 0; e < NE; ++e) {
    float a = l[e] * inv;
    attn[b * NE + e] = a;
    float lg = logf(a + 1e-10f);
    loss += fminf(fmaxf(lg, -6.f), 0.f);
  }
  for (int off = 1; off < 64; off <<= 1) loss += __shfl_xor(loss, off, 64);
  if ((threadIdx.x & 63) == 0) atomicAdd(lossOut, loss * (-0.3f / NB));
}

// tower_in[b,k] = sum_e attn[b,e] * bv1[e,k]   (rank-16 bias init)
__global__ void towerbias_k(const float* __restrict__ attn, const float* __restrict__ bv1,
                            float* __restrict__ towerin) {
  int idx = blockIdx.x * blockDim.x + threadIdx.x;
  if (idx >= NB * DK) return;
  int b = idx >> 9, k = idx & (DK - 1);
  float s = 0.f;
#pragma unroll
  for (int e = 0; e < NE; ++e) s += attn[b * NE + e] * bv1[e * DK + k];
  towerin[idx] = s;
}

// ti = bf16(twin + P0 + P1 + P2 + P3), 8 elems/thread
__global__ void cvt_ti_k(const float* __restrict__ twin, const float* __restrict__ P,
                         unsigned short* __restrict__ ti) {
  int idx = (blockIdx.x * blockDim.x + threadIdx.x) * 8;
  if (idx >= NB * DK) return;
  float v[8];
#pragma unroll
  for (int j = 0; j < 8; ++j) v[j] = twin[idx + j];
#pragma unroll
  for (int c = 0; c < 4; ++c) {
    const float* p = P + (size_t)c * NB * DK + idx;
#pragma unroll
    for (int j = 0; j < 8; ++j) v[j] += p[j];
  }
  unsigned short v8[8];
#pragma unroll
  for (int j = 0; j < 8; ++j) v8[j] = f2bf(v[j]);
  *reinterpret_cast<s8v*>(ti + idx) = *reinterpret_cast<const s8v*>(v8);
}

// wave per row: q[b] = h2[b,:] . Wt2 + bt2
__global__ void qfinal_k(const unsigned short* __restrict__ h2, const float* __restrict__ Wt2,
                         const float* __restrict__ bt2, float* __restrict__ out) {
  int w = (blockIdx.x * blockDim.x + threadIdx.x) >> 6;
  int lane = threadIdx.x & 63;
  if (w >= NB) return;
  float s = 0.f;
#pragma unroll
  for (int j = 0; j < 4; ++j) {
    int k = lane * 4 + j;
    s += bf2f(h2[(size_t)w * 256 + k]) * Wt2[k];
  }
  for (int off = 1; off < 64; off <<= 1) s += __shfl_xor(s, off, 64);
  if (lane == 0) out[w] = s + bt2[0];
}

// ---------------------------------------------------------------------------
extern "C" void kernel_launch(void* const* d_in, const int* in_sizes, int n_in,
                              void* d_out, int out_size, void* d_ws, size_t ws_size,
                              hipStream_t stream) {
  const float* state  = (const float*)d_in[0];
  const float* act    = (const float*)d_in[1];
  const float* rep_W0 = (const float*)d_in[2];
  const float* rep_b0 = (const float*)d_in[3];
  const float* rep_W1 = (const float*)d_in[4];
  const float* rep_b1 = (const float*)d_in[5];
  const float* emb    = (const float*)d_in[6];
  const float* Wk0    = (const float*)d_in[7];
  const float* bk0    = (const float*)d_in[8];
  const float* Wk1    = (const float*)d_in[9];
  const float* bk1    = (const float*)d_in[10];
  const float* Wv0    = (const float*)d_in[11];
  const float* bv0    = (const float*)d_in[12];
  const float* Wv1    = (const float*)d_in[13];
  const float* bv1    = (const float*)d_in[14];
  const float* Wt0    = (const float*)d_in[15];
  const float* bt0    = (const float*)d_in[16];
  const float* Wt1    = (const float*)d_in[17];
  const float* bt1    = (const float*)d_in[18];
  const float* Wt2    = (const float*)d_in[19];
  const float* bt2    = (const float*)d_in[20];
  float* out = (float*)d_out;

  char* wsb = (char*)d_ws;
  size_t off = 0;
  auto alloc = [&](size_t bytes) -> void* {
    void* p = wsb + off;
    off += (bytes + 255) & ~(size_t)255;
    return p;
  };
  unsigned short* Ap    = (unsigned short*)alloc((size_t)NB * 8192 * 2);       // scaled hv, 8 experts
  unsigned short* Wk0t  = (unsigned short*)alloc((size_t)NE * DREP * DH * 2);
  unsigned short* Wv0t  = (unsigned short*)alloc((size_t)NE * DREP * DH * 2);
  unsigned short* Wv1t  = (unsigned short*)alloc((size_t)DK * (NE * DH) * 2);  // [n][e*1024+h]
  float*          P     = (float*)alloc((size_t)4 * NB * DK * 4);              // split-K partials
  unsigned short* h0    = (unsigned short*)alloc((size_t)NB * DREP * 2);
  unsigned short* rep   = (unsigned short*)alloc((size_t)NB * DREP * 2);
  float*          twin  = (float*)alloc((size_t)NB * DK * 4);
  unsigned short* xbuf  = (unsigned short*)alloc((size_t)NB * XK * 2);
  unsigned short* ti    = (unsigned short*)alloc((size_t)NB * DK * 2);
  unsigned short* h1    = (unsigned short*)alloc((size_t)NB * 512 * 2);
  unsigned short* h2    = (unsigned short*)alloc((size_t)NB * 256 * 2);
  unsigned short* rW1t  = (unsigned short*)alloc((size_t)DREP * DREP * 2);
  unsigned short* rW0t  = (unsigned short*)alloc((size_t)DREP * XK * 2);
  float*          qk1   = (float*)alloc((size_t)NE * NT * DH * 4);
  unsigned short* Wt0t  = (unsigned short*)alloc((size_t)512 * 512 * 2);
  unsigned short* Wt1t  = (unsigned short*)alloc((size_t)256 * 512 * 2);
  float*          logits= (float*)alloc((size_t)NB * NE * 4);
  float*          attn  = (float*)alloc((size_t)NB * NE * 4);
  float*          Qt    = (float*)alloc((size_t)NT * DK * 4);
  int*            task  = (int*)alloc((size_t)NB * 4);
  float*          qb    = (float*)alloc((size_t)NE * NT * 4);

  hipMemsetAsync(logits, 0, (size_t)NB * NE * 4, stream);
  hipMemsetAsync(out + NB, 0, sizeof(float), stream);

  task_k<<<NB / 256, 256, 0, stream>>>(state, task);
  buildx_k<<<(NB * XK + 255) / 256, 256, 0, stream>>>(state, act, xbuf);
  prep_emb_k<<<NT, 256, 0, stream>>>(emb, bk1, Qt, qb);
  qk1_k<<<NE * DH / 4, 256, 0, stream>>>(Wk1, Qt, qk1);

  // transposes: grid (N/64, K/64, E)
  convT_k<<<dim3(DREP / 64, XK / 64, 1), 256, 0, stream>>>(rep_W0, rW0t, DREP, 0, 0, XK);
  convT_k<<<dim3(DREP / 64, DREP / 64, 1), 256, 0, stream>>>(rep_W1, rW1t, DREP, 0, 0, DREP);
  convT_k<<<dim3(DH / 64, DREP / 64, NE), 256, 0, stream>>>(Wk0, Wk0t, DH, (long)DREP * DH, (long)DREP * DH, DREP);
  convT_k<<<dim3(DH / 64, DREP / 64, NE), 256, 0, stream>>>(Wv0, Wv0t, DH, (long)DREP * DH, (long)DREP * DH, DREP);
  convT_k<<<dim3(DK / 64, DH / 64, NE), 256, 0, stream>>>(Wv1, Wv1t, DK, (long)DH * DK, 1024L, NE * DH);
  convT_k<<<dim3(512 / 64, 512 / 64, 1), 256, 0, stream>>>(Wt0, Wt0t, 512, 0, 0, 512);
  convT_k<<<dim3(256 / 64, 512 / 64, 1), 256, 0, stream>>>(Wt1, Wt1t, 256, 0, 0, 512);

  // rep MLP (128-tile kernel)
  gemm_k<128, 128, 0, 1, XK, XK, XK><<<dim3(NB / 128, DREP / 128, 1), 256, 0, stream>>>(
      xbuf, rW0t, rep_b0, h0, DREP, nullptr, nullptr, nullptr, 0, nullptr, nullptr);
  gemm_k<128, 128, 0, 0, DREP, DREP, DREP><<<dim3(NB / 128, DREP / 128, 1), 256, 0, stream>>>(
      h0, rW1t, rep_b1, rep, DREP, nullptr, nullptr, nullptr, 0, nullptr, nullptr);

  // K-pass: hk fused into logits (256-tile kernel)
  gemm256_k<1, DREP, DREP, DREP><<<dim3(NB / 256, DH / 256, NE), 512, 0, stream>>>(
      rep, Wk0t, bk0, nullptr, 0, qk1, task, logits, 0, nullptr);

  softmax_k<<<NB / 256, 256, 0, stream>>>(logits, qb, task, attn, out + NB);
  towerbias_k<<<NB * DK / 256, 256, 0, stream>>>(attn, bv1, twin);

  // V-pass (256-tile) + split-K accumulate into per-chunk partials
  for (int g = 0; g < 2; ++g) {
    gemm256_k<2, DREP, DREP, DREP><<<dim3(NB / 256, DH / 256, 8), 512, 0, stream>>>(
        rep, Wv0t, bv0, Ap, 8192, nullptr, nullptr, nullptr, g * 8, attn);
    if (g == 0)
      gemm_k<128, 128, 3, 0, 8192, NE * DH, 2048><<<dim3(NB / 128, DK / 128, 4), 256, 0, stream>>>(
          Ap, Wv1t, nullptr, nullptr, 0, nullptr, nullptr, nullptr, 0, nullptr, P);
    else
      gemm_k<128, 128, 4, 0, 8192, NE * DH, 2048><<<dim3(NB / 128, DK / 128, 4), 256, 0, stream>>>(
          Ap, Wv1t + (size_t)8192, nullptr, nullptr, 0, nullptr, nullptr, nullptr, 0, nullptr, P);
  }
  cvt_ti_k<<<(NB * DK / 8 + 255) / 256, 256, 0, stream>>>(twin, P, ti);

  // tower
  gemm_k<64, 64, 0, 1, DK, DK, DK><<<dim3(NB / 64, 512 / 64, 1), 256, 0, stream>>>(
      ti, Wt0t, bt0, h1, 512, nullptr, nullptr, nullptr, 0, nullptr, nullptr);
  gemm_k<64, 64, 0, 1, 512, 512, 512><<<dim3(NB / 64, 256 / 64, 1), 256, 0, stream>>>(
      h1, Wt1t, bt1, h2, 256, nullptr, nullptr, nullptr, 0, nullptr, nullptr);
  qfinal_k<<<NB / 4, 256, 0, stream>>>(h2, Wt2, bt2, out);
}

// Round 5
// 716.497 us; speedup vs baseline: 1.1417x; 1.1417x over previous
//
#include <hip/hip_runtime.h>
#include <cstdint>
#include <cstddef>

#define NB   4096
#define OBS  512
#define NACT 64
#define NT   10
#define NE   16
#define DREP 1024
#define DH   1024
#define DK   512
#define SLD  (OBS + NT)    // 522, state row length
#define XK   (OBS + NACT)  // 576

typedef short s8v __attribute__((ext_vector_type(8)));  // 8 bf16 in 4 VGPRs
typedef float f4v __attribute__((ext_vector_type(4)));

__device__ __forceinline__ unsigned short f2bf(float f) {
  union { float f; unsigned int u; } v; v.f = f;
  unsigned int u = v.u;
  unsigned int r = (u + 0x7FFFu + ((u >> 16) & 1u)) >> 16;  // RNE
  return (unsigned short)r;
}
__device__ __forceinline__ float bf2f(unsigned short h) {
  union { unsigned int u; float f; } v; v.u = ((unsigned int)h) << 16;
  return v.f;
}

__device__ __forceinline__ void gload_lds16(const unsigned short* gp, const unsigned short* lp) {
  __builtin_amdgcn_global_load_lds(
      (const __attribute__((address_space(1))) void*)(uintptr_t)gp,
      (__attribute__((address_space(3))) void*)(unsigned int)(uintptr_t)lp,
      16, 0, 0);
}

// ---------------------------------------------------------------------------
// Generic bf16 GEMM: C[M,N] = A[M,K] @ Bt[N,K]^T  (Bt is N-major, K contiguous)
// 3-stage pipelined K-loop, 128x128 tile, 4 waves. Kept for rep-MLP, split-K
// V2 (MODE 3/4) and tower.
// MODE 0: out = bf16(maybe_relu(C + bias[col]))
// MODE 3 (split-K partial write): P[z][row][col]  = C
// MODE 4 (split-K partial add):   P[z][row][col] += C
// ---------------------------------------------------------------------------
template <int BM, int BN, int MODE, int RELU, int LDA, int LDB, int KK>
__global__ void __launch_bounds__(256)
gemm_k(const unsigned short* __restrict__ A,
       const unsigned short* __restrict__ Bt,
       const float* __restrict__ bias,
       unsigned short* __restrict__ outB, int ldo,
       const float* __restrict__ qk1, const int* __restrict__ task,
       float* __restrict__ logits, int eBase,
       const float* __restrict__ attn, float* __restrict__ cio)
{
  constexpr int FM = BM / 32;   // 16x16 frags per wave (M)
  constexpr int FN = BN / 32;
  constexpr int CA = BM / 64;   // 1KB staging chunks per wave (A)
  constexpr int CB = BN / 64;
  constexpr int NTILES = KK / 32;
  static_assert(NTILES >= 3, "pipeline depth");
  constexpr int LPS = CA + CB;           // loads per stage per wave
  static_assert(LPS < 16, "vmcnt immediate fits in low bits");
  constexpr int WAIT_STAGE = 0xF70 | LPS;  // vmcnt(LPS): prev stage done
  constexpr int WAIT_ALL   = 0xF70;        // vmcnt(0): drain (tail only)

  __shared__ __align__(16) unsigned short As[3][BM * 32];
  __shared__ __align__(16) unsigned short Bs[3][BN * 32];

  const int tid  = threadIdx.x;
  const int wave = tid >> 6;
  const int lane = tid & 63;
  const int wm = wave >> 1, wn = wave & 1;

  const int rowBase = blockIdx.x * BM;
  const int colBase = blockIdx.y * BN;

  if (MODE == 3 || MODE == 4) {
    A   += (size_t)blockIdx.z * KK;    // K-chunk
    Bt  += (size_t)blockIdx.z * KK;
    cio += (size_t)blockIdx.z * NB * DK;
  }

  f4v acc[FM][FN];
#pragma unroll
  for (int m = 0; m < FM; ++m)
#pragma unroll
    for (int n = 0; n < FN; ++n) acc[m][n] = f4v{0.f, 0.f, 0.f, 0.f};

  const int sRow = lane >> 2;                                 // row within 16-row chunk
  const int sSw  = ((lane & 3) ^ ((sRow >> 1) & 3)) * 8;      // swizzled global k-offset

  const unsigned short* ag[CA];
  const unsigned short* bg[CB];
#pragma unroll
  for (int j = 0; j < CA; ++j)
    ag[j] = A + (size_t)(rowBase + (wave * CA + j) * 16 + sRow) * LDA + sSw;
#pragma unroll
  for (int j = 0; j < CB; ++j)
    bg[j] = Bt + (size_t)(colBase + (wave * CB + j) * 16 + sRow) * LDB + sSw;

  const int fr   = lane & 15;
  const int koSw = ((lane >> 4) ^ ((fr >> 1) & 3)) * 8;       // swizzled read slot
  const int aOff = (wm * (BM / 2) + fr) * 32 + koSw;
  const int bOff = (wn * (BN / 2) + fr) * 32 + koSw;

  auto stage = [&](int buf) {
#pragma unroll
    for (int j = 0; j < CA; ++j) { gload_lds16(ag[j], &As[buf][(wave * CA + j) * 512]); ag[j] += 32; }
#pragma unroll
    for (int j = 0; j < CB; ++j) { gload_lds16(bg[j], &Bs[buf][(wave * CB + j) * 512]); bg[j] += 32; }
  };

  auto compute = [&](int buf) {
    s8v av[FM], bv[FN];
#pragma unroll
    for (int m = 0; m < FM; ++m)
      av[m] = *reinterpret_cast<const s8v*>(&As[buf][aOff + m * 512]);
#pragma unroll
    for (int n = 0; n < FN; ++n)
      bv[n] = *reinterpret_cast<const s8v*>(&Bs[buf][bOff + n * 512]);
#pragma unroll
    for (int m = 0; m < FM; ++m)
#pragma unroll
      for (int n = 0; n < FN; ++n)
        acc[m][n] = __builtin_amdgcn_mfma_f32_16x16x32_bf16(av[m], bv[n], acc[m][n], 0, 0, 0);
  };

  stage(0);   // tile 0
  stage(1);   // tile 1

  for (int t = 0; t < NTILES; t += 3) {
    // ---- tile t (buf 0) ----
    if (t + 1 < NTILES) __builtin_amdgcn_s_waitcnt(WAIT_STAGE);
    else                __builtin_amdgcn_s_waitcnt(WAIT_ALL);
    __builtin_amdgcn_s_barrier();
    if (t + 2 < NTILES) stage(2);
    compute(0);
    // ---- tile t+1 (buf 1) ----
    if (t + 1 < NTILES) {
      if (t + 2 < NTILES) __builtin_amdgcn_s_waitcnt(WAIT_STAGE);
      else                __builtin_amdgcn_s_waitcnt(WAIT_ALL);
      __builtin_amdgcn_s_barrier();
      if (t + 3 < NTILES) stage(0);
      compute(1);
    }
    // ---- tile t+2 (buf 2) ----
    if (t + 2 < NTILES) {
      if (t + 3 < NTILES) __builtin_amdgcn_s_waitcnt(WAIT_STAGE);
      else                __builtin_amdgcn_s_waitcnt(WAIT_ALL);
      __builtin_amdgcn_s_barrier();
      if (t + 4 < NTILES) stage(1);
      compute(2);
    }
  }

  // ---------------- epilogue ----------------
  const int cr = (lane >> 4) * 4;  // row base within fragment
  const int cc = lane & 15;        // col within fragment

  int gcn[FN];
  float bcol[FN];
#pragma unroll
  for (int n = 0; n < FN; ++n) {
    gcn[n] = colBase + wn * (BN / 2) + n * 16 + cc;
    bcol[n] = (MODE >= 3) ? 0.f : bias[gcn[n]];
  }

  if (MODE == 0) {
#pragma unroll
    for (int m = 0; m < FM; ++m)
#pragma unroll
      for (int r = 0; r < 4; ++r) {
        int gr = rowBase + wm * (BM / 2) + m * 16 + cr + r;
#pragma unroll
        for (int n = 0; n < FN; ++n) {
          float v = acc[m][n][r] + bcol[n];
          if (RELU) v = fmaxf(v, 0.f);
          outB[(size_t)gr * ldo + gcn[n]] = f2bf(v);
        }
      }
  }

  if (MODE == 3 || MODE == 4) {
#pragma unroll
    for (int m = 0; m < FM; ++m)
#pragma unroll
      for (int r = 0; r < 4; ++r) {
        int gr = rowBase + wm * (BM / 2) + m * 16 + cr + r;
#pragma unroll
        for (int n = 0; n < FN; ++n) {
          float v = acc[m][n][r];
          if (MODE == 4) v += cio[(size_t)gr * DK + gcn[n]];
          cio[(size_t)gr * DK + gcn[n]] = v;
        }
      }
  }
}

// ---------------------------------------------------------------------------
// 256x256-tile, BK=64, 8-wave GEMM — REVERTED to the R3/v3 version: one
// barrier per K-tile, drain-vmcnt at tile end, prefetch distance 1.
// Best measured: 160 µs K-pass, MfmaUtil 37%, SQ_LDS_BANK_CONFLICT = 0.
// R4's BK=32 tri-buffer experiment regressed (242 µs): its 64B-row layout
// broke the XOR swizzle (chunk^(row&3) spans only 16 banks -> 4-way conflict,
// 1.26e7 conflicts/dispatch).  The BK=64 layout here spans all 32 banks
// (128B row, 8-slot XOR) and is verified conflict-free.  Schedule surgery on
// this kernel is parked: three variants (R1/R2/R3) all pin at 34-37%.
// MODE 1 (K-pass): v=relu(C+bk0[e,col]); logits[row,e] += v*qk1[e,task,col]
// MODE 2 (V-pass): out = bf16(attn[row,e] * relu(C + bv0[e,col]))
// ---------------------------------------------------------------------------
template <int MODE, int LDA, int LDB, int KK>
__global__ void __launch_bounds__(512)
gemm256_k(const unsigned short* __restrict__ A,
          const unsigned short* __restrict__ Bt,
          const float* __restrict__ bias,
          unsigned short* __restrict__ outB, int ldo,
          const float* __restrict__ qk1, const int* __restrict__ task,
          float* __restrict__ logits, int eBase,
          const float* __restrict__ attn)
{
  constexpr int NTK = KK / 64;
  static_assert(NTK >= 4 && (NTK & 1) == 0, "pipeline depth");

  __shared__ __align__(16) unsigned short As[2][16384];  // [buf][row*64 + swz k]
  __shared__ __align__(16) unsigned short Bs[2][16384];

  const int tid  = threadIdx.x;
  const int wave = tid >> 6;
  const int lane = tid & 63;
  const int l3 = lane >> 3, l7 = lane & 7, l4 = lane >> 4;

  // ---- XCD-bijective block swizzle (requires nwg % 8 == 0; holds here) ----
  const int gx = gridDim.x, gy = gridDim.y;
  int flat = blockIdx.x + gx * (blockIdx.y + gy * blockIdx.z);
  const int nwg = gx * gy * gridDim.z;
  flat = (flat & 7) * (nwg >> 3) + (flat >> 3);
  const int bx = flat % gx; flat /= gx;
  const int by = flat % gy;
  const int bz = flat / gy;

  const int rowBase = bx * 256;
  const int colBase = by * 256;

  int eg = 0;
  if (MODE == 1) {
    eg = bz;
    Bt   += (size_t)eg * ((size_t)DREP * DH);
    bias += eg * DH;
    qk1  += (size_t)eg * (NT * DH);
  }
  if (MODE == 2) {
    eg = eBase + bz;
    Bt   += (size_t)eg * ((size_t)DREP * DH);
    bias += eg * DH;
    outB += (size_t)bz * DH;   // local slab in Ap
  }

  f4v acc[2][2][2][4];   // [qm][qn][f][fc]
#pragma unroll
  for (int i0 = 0; i0 < 2; ++i0)
#pragma unroll
    for (int i1 = 0; i1 < 2; ++i1)
#pragma unroll
      for (int i2 = 0; i2 < 2; ++i2)
#pragma unroll
        for (int i3 = 0; i3 < 4; ++i3)
          acc[i0][i1][i2][i3] = f4v{0.f, 0.f, 0.f, 0.f};

  // ---- persistent staging pointers: [half][j], bump += 64 shorts per tile.
  const unsigned short* pA[2][2];
  const unsigned short* pB[2][2];
#pragma unroll
  for (int h = 0; h < 2; ++h)
#pragma unroll
    for (int j = 0; j < 2; ++j) {
      const int r  = h * 128 + j * 64 + wave * 8 + l3;
      const int ks = (l7 ^ l3) * 8;
      pA[h][j] = A  + (size_t)(rowBase + r) * LDA + ks;
      pB[h][j] = Bt + (size_t)(colBase + r) * LDB + ks;
    }

  auto stageA = [&](int buf, int h) {
#pragma unroll
    for (int j = 0; j < 2; ++j) {
      gload_lds16(pA[h][j], &As[buf][h * 8192 + j * 4096 + wave * 512]);
      pA[h][j] += 64;
    }
  };
  auto stageB = [&](int buf, int h) {
#pragma unroll
    for (int j = 0; j < 2; ++j) {
      gload_lds16(pB[h][j], &Bs[buf][h * 8192 + j * 4096 + wave * 512]);
      pB[h][j] += 64;
    }
  };

  // ---- LDS -> fragment reads (swizzle-aware) ----
  const int cOff0 = (l4 ^ l7) * 8;
  const int cOff1 = ((4 + l4) ^ l7) * 8;
  const int aRowOff = ((wave & 3) * 32 + (lane & 15)) * 64;
  const int bColOff = ((wave >> 2) * 64 + (lane & 15)) * 64;

  s8v avA[2][2], avB[2][2], bv[4][2];   // avA=A-half0 (lives whole tile), avB=A-half1, bv=B0 then B1
  auto readAh = [&](int buf, int h, s8v (&av)[2][2]) {
#pragma unroll
    for (int f = 0; f < 2; ++f) {
      const unsigned short* p = &As[buf][h * 8192 + aRowOff + f * 1024];
      av[f][0] = *reinterpret_cast<const s8v*>(p + cOff0);
      av[f][1] = *reinterpret_cast<const s8v*>(p + cOff1);
    }
  };
  auto readB = [&](int buf, int qn) {
#pragma unroll
    for (int fc = 0; fc < 4; ++fc) {
      const unsigned short* p = &Bs[buf][qn * 8192 + bColOff + fc * 1024];
      bv[fc][0] = *reinterpret_cast<const s8v*>(p + cOff0);
      bv[fc][1] = *reinterpret_cast<const s8v*>(p + cOff1);
    }
  };

#define MFMA_BLK(QM, QN, AV)                                                  \
  do {                                                                        \
    __builtin_amdgcn_s_setprio(1);                                            \
    _Pragma("unroll") for (int ks_ = 0; ks_ < 2; ++ks_)                       \
      _Pragma("unroll") for (int f_ = 0; f_ < 2; ++f_)                        \
        _Pragma("unroll") for (int fc_ = 0; fc_ < 4; ++fc_)                   \
          acc[QM][QN][f_][fc_] = __builtin_amdgcn_mfma_f32_16x16x32_bf16(     \
              AV[f_][ks_], bv[fc_][ks_], acc[QM][QN][f_][fc_], 0, 0, 0);      \
    __builtin_amdgcn_s_setprio(0);                                            \
  } while (0)

  auto tile_body = [&](int t, int buf) __attribute__((always_inline)) {
    readAh(buf, 1, avB);                       // A1 reads overlap MFMA(0,0)
    if (t + 1 < NTK) {                         // stage ALL of tile t+1 early
      stageA(buf ^ 1, 0); stageB(buf ^ 1, 0);
      stageA(buf ^ 1, 1); stageB(buf ^ 1, 1);
    }
    MFMA_BLK(0, 0, avA);                       // lgkm waits A0,B0 only
    MFMA_BLK(1, 0, avB);                       // lgkm waits A1
    readB(buf, 1);                             // B1 -> bv (after (1,0) uses B0)
    MFMA_BLK(1, 1, avB);                       // lgkm waits B1
    MFMA_BLK(0, 1, avA);
    if (t + 1 < NTK) {
      __builtin_amdgcn_s_waitcnt(0xF70);       // vmcnt(0): t+1 fully resident
      __builtin_amdgcn_s_barrier();            // the ONLY barrier per tile
      readAh(buf ^ 1, 0, avA);                 // A0 of t+1
      readB(buf ^ 1, 0);                       // B0 of t+1
    }
  };

  // ---- prologue: stage tile0 (4 halves), drain, issue first frag reads ----
  stageA(0, 0); stageB(0, 0); stageA(0, 1); stageB(0, 1);
  __builtin_amdgcn_s_waitcnt(0xF70);
  __builtin_amdgcn_s_barrier();
  readAh(0, 0, avA);
  readB(0, 0);

  for (int t = 0; t < NTK; t += 2) {
    tile_body(t, 0);
    tile_body(t + 1, 1);
  }
#undef MFMA_BLK

  // ---------------- epilogue ----------------
  const int cr = l4 * 4;
  const int cc = lane & 15;

  int gcn[2][4];
  float bcol[2][4];
#pragma unroll
  for (int qn = 0; qn < 2; ++qn)
#pragma unroll
    for (int fc = 0; fc < 4; ++fc) {
      gcn[qn][fc]  = colBase + qn * 128 + (wave >> 2) * 64 + fc * 16 + cc;
      bcol[qn][fc] = bias[gcn[qn][fc]];
    }

  if (MODE == 1) {
#pragma unroll
    for (int qm = 0; qm < 2; ++qm)
#pragma unroll
      for (int f = 0; f < 2; ++f)
#pragma unroll
        for (int r = 0; r < 4; ++r) {
          const int gr = rowBase + qm * 128 + (wave & 3) * 32 + f * 16 + cr + r;
          const float* qrow = qk1 + (size_t)task[gr] * DH;
          float s = 0.f;
#pragma unroll
          for (int qn = 0; qn < 2; ++qn)
#pragma unroll
            for (int fc = 0; fc < 4; ++fc) {
              float v = fmaxf(acc[qm][qn][f][fc][r] + bcol[qn][fc], 0.f);
              s += v * qrow[gcn[qn][fc]];
            }
#pragma unroll
          for (int off = 1; off < 16; off <<= 1) s += __shfl_xor(s, off, 64);
          if (cc == 0) atomicAdd(&logits[gr * NE + eg], s);
        }
  }

  if (MODE == 2) {
#pragma unroll
    for (int qm = 0; qm < 2; ++qm)
#pragma unroll
      for (int f = 0; f < 2; ++f)
#pragma unroll
        for (int r = 0; r < 4; ++r) {
          const int gr = rowBase + qm * 128 + (wave & 3) * 32 + f * 16 + cr + r;
          const float aw = attn[gr * NE + eg];
#pragma unroll
          for (int qn = 0; qn < 2; ++qn)
#pragma unroll
            for (int fc = 0; fc < 4; ++fc) {
              float v = fmaxf(acc[qm][qn][f][fc][r] + bcol[qn][fc], 0.f) * aw;
              outB[(size_t)gr * ldo + gcn[qn][fc]] = f2bf(v);
            }
        }
  }
}

// ---------------------------------------------------------------------------
// front_k: fused {task argmax | buildx bf16 pack | qb dot | Qt tanh} by
// blockIdx range.  All four roles are independent (qk1_k consumes Qt in the
// NEXT launch).  Saves 3 dispatches + their gaps.
// blocks [0,16): task.  [16,1168): buildx 8 elems/thread (s8v stores).
// [1168,1208): qb, wave per (e,t), tanh recomputed (Qt not yet visible).
// [1208,1228): Qt = tanh(emb), 5120 elems.
// ---------------------------------------------------------------------------
__global__ void __launch_bounds__(256)
front_k(const float* __restrict__ state, const float* __restrict__ act,
        const float* __restrict__ emb, const float* __restrict__ bk1,
        unsigned short* __restrict__ x, int* __restrict__ task,
        float* __restrict__ Qt, float* __restrict__ qb)
{
  const int blk = blockIdx.x, tid = threadIdx.x;
  if (blk < 16) {                      // ---- task argmax ----
    int b = blk * 256 + tid;
    const float* p = state + (size_t)b * SLD + OBS;
    float best = p[0]; int bi = 0;
    for (int j = 1; j < NT; ++j) { float v = p[j]; if (v > best) { best = v; bi = j; } }
    task[b] = bi;
  } else if (blk < 16 + 1152) {        // ---- buildx, vectorized ----
    int idx8 = (blk - 16) * 256 + tid;            // < 4096*72
    int b = idx8 / 72, c8 = idx8 - b * 72, j = c8 * 8;
    float v[8];
    if (j < OBS) {
      const float* s = state + (size_t)b * SLD + j;
#pragma unroll
      for (int q = 0; q < 8; ++q) v[q] = s[q];
    } else {
      const float* a = act + (size_t)b * NACT + (j - OBS);
#pragma unroll
      for (int q = 0; q < 8; ++q) v[q] = a[q];
    }
    unsigned short v8[8];
#pragma unroll
    for (int q = 0; q < 8; ++q) v8[q] = f2bf(v[q]);
    *reinterpret_cast<s8v*>(x + (size_t)b * XK + j) = *reinterpret_cast<const s8v*>(v8);
  } else if (blk < 16 + 1152 + 40) {   // ---- qb[e,t] = tanh(emb[t]).bk1[e] ----
    int w = (blk - 1168) * 4 + (tid >> 6), lane = tid & 63;   // w < 160
    int e = w / NT, t = w - e * NT;
    const float* ep = emb + t * DK + lane * 8;
    const float* bp = bk1 + e * DK + lane * 8;
    float s = 0.f;
#pragma unroll
    for (int q = 0; q < 8; ++q) s += tanhf(ep[q]) * bp[q];
    for (int off = 1; off < 64; off <<= 1) s += __shfl_xor(s, off, 64);
    if (lane == 0) qb[e * NT + t] = s;
  } else {                             // ---- Qt = tanh(emb) ----
    int idx = (blk - 1208) * 256 + tid;           // < NT*DK = 5120 exactly
    Qt[idx] = tanhf(emb[idx]);
  }
}

// wave per (e,h): qk1[e,t,h] = sum_k Wk1[e,h,k] * Qt[t,k]
__global__ void qk1_k(const float* __restrict__ Wk1, const float* __restrict__ Qt,
                      float* __restrict__ qk1) {
  int w = (blockIdx.x * blockDim.x + threadIdx.x) >> 6;
  int lane = threadIdx.x & 63;
  if (w >= NE * DH) return;
  int e = w >> 10, h = w & (DH - 1);
  const float* wrow = Wk1 + ((size_t)e * DH + h) * DK + lane * 8;
  float wv[8];
#pragma unroll
  for (int j = 0; j < 8; ++j) wv[j] = wrow[j];
#pragma unroll
  for (int t = 0; t < NT; ++t) {
    const float* qrow = Qt + t * DK + lane * 8;
    float s = 0.f;
#pragma unroll
    for (int j = 0; j < 8; ++j) s += wv[j] * qrow[j];
#pragma unroll
    for (int off = 1; off < 64; off <<= 1) s += __shfl_xor(s, off, 64);
    if (lane == 0) qk1[((size_t)e * NT + t) * DH + h] = s;
  }
}

// ---------------------------------------------------------------------------
// convT_all_k: ALL 7 weight transposes (fp32 -> bf16, [K][N] -> [N][K]) in
// ONE launch, job selected by flat blockIdx range (saves 6 dispatches).
// Body identical to the old convT_k: 64x64 tile via LDS [64][65].
// Job table (compile-time): {tiles, tpe, N, sBS, dBS, dLd, nx}
//   0 rep_W0->rW0t : 144  (16x9)      N=1024 dLd=576
//   1 rep_W1->rW1t : 256  (16x16)     N=1024 dLd=1024
//   2 Wk0  ->Wk0t  : 4096 (16x16x16)  N=1024 dLd=1024  BS=1M
//   3 Wv0  ->Wv0t  : 4096             N=1024 dLd=1024  BS=1M
//   4 Wv1  ->Wv1t  : 2048 (8x16x16)   N=512  dLd=16384 sBS=512K dBS=1024
//   5 Wt0  ->Wt0t  : 64   (8x8)       N=512  dLd=512
//   6 Wt1  ->Wt1t  : 32   (4x8)       N=256  dLd=512
// ---------------------------------------------------------------------------
__global__ void __launch_bounds__(256)
convT_all_k(const float* __restrict__ W0,  unsigned short* __restrict__ dW0,
            const float* __restrict__ W1,  unsigned short* __restrict__ dW1,
            const float* __restrict__ Wk0, unsigned short* __restrict__ dWk0,
            const float* __restrict__ Wv0, unsigned short* __restrict__ dWv0,
            const float* __restrict__ Wv1, unsigned short* __restrict__ dWv1,
            const float* __restrict__ Wt0, unsigned short* __restrict__ dWt0,
            const float* __restrict__ Wt1, unsigned short* __restrict__ dWt1)
{
  int id = blockIdx.x;
  const float* src; unsigned short* dst;
  int N, dLd, nx, tpe; long sBS, dBS;
  if (id < 144)        {            src = W0;  dst = dW0;  N = 1024; sBS = 0; dBS = 0; dLd = 576;   nx = 16; tpe = 144; }
  else if (id < 400)   { id -= 144; src = W1;  dst = dW1;  N = 1024; sBS = 0; dBS = 0; dLd = 1024;  nx = 16; tpe = 256; }
  else if (id < 4496)  { id -= 400; src = Wk0; dst = dWk0; N = 1024; sBS = (long)DREP * DH; dBS = (long)DREP * DH; dLd = 1024; nx = 16; tpe = 256; }
  else if (id < 8592)  { id -= 4496; src = Wv0; dst = dWv0; N = 1024; sBS = (long)DREP * DH; dBS = (long)DREP * DH; dLd = 1024; nx = 16; tpe = 256; }
  else if (id < 10640) { id -= 8592; src = Wv1; dst = dWv1; N = 512;  sBS = (long)DH * DK; dBS = 1024; dLd = NE * DH; nx = 8; tpe = 128; }
  else if (id < 10704) { id -= 10640; src = Wt0; dst = dWt0; N = 512; sBS = 0; dBS = 0; dLd = 512; nx = 8; tpe = 64; }
  else                 { id -= 10704; src = Wt1; dst = dWt1; N = 256; sBS = 0; dBS = 0; dLd = 512; nx = 4; tpe = 32; }
  const int e  = id / tpe;
  const int r  = id - e * tpe;
  const int n0 = (r % nx) * 64, k0 = (r / nx) * 64;

  __shared__ float tile[64][65];
  src += (size_t)e * sBS + (size_t)k0 * N + n0;
  dst += (size_t)e * dBS + (size_t)n0 * dLd + k0;
  int t = threadIdx.x;
  int c4 = t & 15, kr = t >> 4;            // 16 float4-cols x 16 rows per pass
#pragma unroll
  for (int i = 0; i < 4; ++i) {
    float4 v = *(const float4*)(src + (size_t)(kr + i * 16) * N + c4 * 4);
    tile[kr + i * 16][c4 * 4 + 0] = v.x;
    tile[kr + i * 16][c4 * 4 + 1] = v.y;
    tile[kr + i * 16][c4 * 4 + 2] = v.z;
    tile[kr + i * 16][c4 * 4 + 3] = v.w;
  }
  __syncthreads();
  int sub = t & 7, nl = t >> 3;            // 8 k-chunks x 32 n per pass
#pragma unroll
  for (int pass = 0; pass < 2; ++pass) {
    int n = nl + pass * 32;
    unsigned short v8[8];
#pragma unroll
    for (int j = 0; j < 8; ++j) v8[j] = f2bf(tile[sub * 8 + j][n]);
    *reinterpret_cast<s8v*>(dst + (size_t)n * dLd + sub * 8) =
        *reinterpret_cast<const s8v*>(v8);
  }
}

// ---------------------------------------------------------------------------
// attn_k: fused softmax + expert-loss + towerbias.  Block = 16 rows; thread
// (rr,e) = one logit.  Softmax reduces across the 16 e-lanes via shfl_xor
// (e = lane&15, so offsets 1..8 stay in-group).  Phase 2: tower_in for the
// same 16 rows (attn from LDS).  Saves 1 dispatch + the attn HBM round-trip
// locality (attn written/needed while L2-hot).
// ---------------------------------------------------------------------------
__global__ void __launch_bounds__(256)
attn_k(const float* __restrict__ logits, const float* __restrict__ qb,
       const int* __restrict__ task, const float* __restrict__ bv1,
       float* __restrict__ attn, float* __restrict__ twin,
       float* __restrict__ lossOut)
{
  __shared__ float aL[16][16];
  __shared__ float lred[4];
  const int tid = threadIdx.x;
  const int rr = tid >> 4, e = tid & 15;
  const int b = blockIdx.x * 16 + rr;
  const int t = task[b];
  float l = logits[b * NE + e] + qb[e * NT + t];
  float mx = l;
#pragma unroll
  for (int off = 1; off < 16; off <<= 1) mx = fmaxf(mx, __shfl_xor(mx, off, 64));
  float ex = expf(l - mx);
  float s = ex;
#pragma unroll
  for (int off = 1; off < 16; off <<= 1) s += __shfl_xor(s, off, 64);
  float a = ex / s;
  attn[b * NE + e] = a;
  aL[rr][e] = a;
  float loss = fminf(fmaxf(logf(a + 1e-10f), -6.f), 0.f);
#pragma unroll
  for (int off = 1; off < 64; off <<= 1) loss += __shfl_xor(loss, off, 64);
  if ((tid & 63) == 0) lred[tid >> 6] = loss;
  __syncthreads();
  if (tid == 0)
    atomicAdd(lossOut, (lred[0] + lred[1] + lred[2] + lred[3]) * (-0.3f / NB));
  // ---- towerbias: twin[b, :] = sum_e attn[b,e] * bv1[e, :] ----
  float av[NE];
#pragma unroll
  for (int q = 0; q < NE; ++q) av[q] = aL[rr][q];
  float* tw = twin + (size_t)b * DK;
  for (int j = 0; j < 32; ++j) {
    int k = e + j * 16;
    float sv = 0.f;
#pragma unroll
    for (int q = 0; q < NE; ++q) sv += av[q] * bv1[q * DK + k];
    tw[k] = sv;
  }
}

// ti = bf16(twin + P0 + P1 + P2 + P3), 8 elems/thread
__global__ void cvt_ti_k(const float* __restrict__ twin, const float* __restrict__ P,
                         unsigned short* __restrict__ ti) {
  int idx = (blockIdx.x * blockDim.x + threadIdx.x) * 8;
  if (idx >= NB * DK) return;
  float v[8];
#pragma unroll
  for (int j = 0; j < 8; ++j) v[j] = twin[idx + j];
#pragma unroll
  for (int c = 0; c < 4; ++c) {
    const float* p = P + (size_t)c * NB * DK + idx;
#pragma unroll
    for (int j = 0; j < 8; ++j) v[j] += p[j];
  }
  unsigned short v8[8];
#pragma unroll
  for (int j = 0; j < 8; ++j) v8[j] = f2bf(v[j]);
  *reinterpret_cast<s8v*>(ti + idx) = *reinterpret_cast<const s8v*>(v8);
}

// wave per row: q[b] = h2[b,:] . Wt2 + bt2
__global__ void qfinal_k(const unsigned short* __restrict__ h2, const float* __restrict__ Wt2,
                         const float* __restrict__ bt2, float* __restrict__ out) {
  int w = (blockIdx.x * blockDim.x + threadIdx.x) >> 6;
  int lane = threadIdx.x & 63;
  if (w >= NB) return;
  float s = 0.f;
#pragma unroll
  for (int j = 0; j < 4; ++j) {
    int k = lane * 4 + j;
    s += bf2f(h2[(size_t)w * 256 + k]) * Wt2[k];
  }
  for (int off = 1; off < 64; off <<= 1) s += __shfl_xor(s, off, 64);
  if (lane == 0) out[w] = s + bt2[0];
}

// ---------------------------------------------------------------------------
extern "C" void kernel_launch(void* const* d_in, const int* in_sizes, int n_in,
                              void* d_out, int out_size, void* d_ws, size_t ws_size,
                              hipStream_t stream) {
  const float* state  = (const float*)d_in[0];
  const float* act    = (const float*)d_in[1];
  const float* rep_W0 = (const float*)d_in[2];
  const float* rep_b0 = (const float*)d_in[3];
  const float* rep_W1 = (const float*)d_in[4];
  const float* rep_b1 = (const float*)d_in[5];
  const float* emb    = (const float*)d_in[6];
  const float* Wk0    = (const float*)d_in[7];
  const float* bk0    = (const float*)d_in[8];
  const float* Wk1    = (const float*)d_in[9];
  const float* bk1    = (const float*)d_in[10];
  const float* Wv0    = (const float*)d_in[11];
  const float* bv0    = (const float*)d_in[12];
  const float* Wv1    = (const float*)d_in[13];
  const float* bv1    = (const float*)d_in[14];
  const float* Wt0    = (const float*)d_in[15];
  const float* bt0    = (const float*)d_in[16];
  const float* Wt1    = (const float*)d_in[17];
  const float* bt1    = (const float*)d_in[18];
  const float* Wt2    = (const float*)d_in[19];
  const float* bt2    = (const float*)d_in[20];
  float* out = (float*)d_out;

  char* wsb = (char*)d_ws;
  size_t off = 0;
  auto alloc = [&](size_t bytes) -> void* {
    void* p = wsb + off;
    off += (bytes + 255) & ~(size_t)255;
    return p;
  };
  unsigned short* Ap    = (unsigned short*)alloc((size_t)NB * 8192 * 2);       // scaled hv, 8 experts
  unsigned short* Wk0t  = (unsigned short*)alloc((size_t)NE * DREP * DH * 2);
  unsigned short* Wv0t  = (unsigned short*)alloc((size_t)NE * DREP * DH * 2);
  unsigned short* Wv1t  = (unsigned short*)alloc((size_t)DK * (NE * DH) * 2);  // [n][e*1024+h]
  float*          P     = (float*)alloc((size_t)4 * NB * DK * 4);              // split-K partials
  unsigned short* h0    = (unsigned short*)alloc((size_t)NB * DREP * 2);
  unsigned short* rep   = (unsigned short*)alloc((size_t)NB * DREP * 2);
  float*          twin  = (float*)alloc((size_t)NB * DK * 4);
  unsigned short* xbuf  = (unsigned short*)alloc((size_t)NB * XK * 2);
  unsigned short* ti    = (unsigned short*)alloc((size_t)NB * DK * 2);
  unsigned short* h1    = (unsigned short*)alloc((size_t)NB * 512 * 2);
  unsigned short* h2    = (unsigned short*)alloc((size_t)NB * 256 * 2);
  unsigned short* rW1t  = (unsigned short*)alloc((size_t)DREP * DREP * 2);
  unsigned short* rW0t  = (unsigned short*)alloc((size_t)DREP * XK * 2);
  float*          qk1   = (float*)alloc((size_t)NE * NT * DH * 4);
  unsigned short* Wt0t  = (unsigned short*)alloc((size_t)512 * 512 * 2);
  unsigned short* Wt1t  = (unsigned short*)alloc((size_t)256 * 512 * 2);
  float*          logits= (float*)alloc((size_t)NB * NE * 4);
  float*          attn  = (float*)alloc((size_t)NB * NE * 4);
  float*          Qt    = (float*)alloc((size_t)NT * DK * 4);
  int*            task  = (int*)alloc((size_t)NB * 4);
  float*          qb    = (float*)alloc((size_t)NE * NT * 4);

  hipMemsetAsync(logits, 0, (size_t)NB * NE * 4, stream);
  hipMemsetAsync(out + NB, 0, sizeof(float), stream);

  // fused front: task | buildx | qb | Qt   (16 + 1152 + 40 + 20 blocks)
  front_k<<<1228, 256, 0, stream>>>(state, act, emb, bk1, xbuf, task, Qt, qb);
  qk1_k<<<NE * DH / 4, 256, 0, stream>>>(Wk1, Qt, qk1);

  // all 7 weight transposes in one launch (10736 blocks)
  convT_all_k<<<10736, 256, 0, stream>>>(rep_W0, rW0t, rep_W1, rW1t,
                                         Wk0, Wk0t, Wv0, Wv0t, Wv1, Wv1t,
                                         Wt0, Wt0t, Wt1, Wt1t);

  // rep MLP (128-tile kernel)
  gemm_k<128, 128, 0, 1, XK, XK, XK><<<dim3(NB / 128, DREP / 128, 1), 256, 0, stream>>>(
      xbuf, rW0t, rep_b0, h0, DREP, nullptr, nullptr, nullptr, 0, nullptr, nullptr);
  gemm_k<128, 128, 0, 0, DREP, DREP, DREP><<<dim3(NB / 128, DREP / 128, 1), 256, 0, stream>>>(
      h0, rW1t, rep_b1, rep, DREP, nullptr, nullptr, nullptr, 0, nullptr, nullptr);

  // K-pass: hk fused into logits (256-tile kernel)
  gemm256_k<1, DREP, DREP, DREP><<<dim3(NB / 256, DH / 256, NE), 512, 0, stream>>>(
      rep, Wk0t, bk0, nullptr, 0, qk1, task, logits, 0, nullptr);

  // fused softmax + loss + towerbias
  attn_k<<<NB / 16, 256, 0, stream>>>(logits, qb, task, bv1, attn, twin, out + NB);

  // V-pass (256-tile) + split-K accumulate into per-chunk partials
  for (int g = 0; g < 2; ++g) {
    gemm256_k<2, DREP, DREP, DREP><<<dim3(NB / 256, DH / 256, 8), 512, 0, stream>>>(
        rep, Wv0t, bv0, Ap, 8192, nullptr, nullptr, nullptr, g * 8, attn);
    if (g == 0)
      gemm_k<128, 128, 3, 0, 8192, NE * DH, 2048><<<dim3(NB / 128, DK / 128, 4), 256, 0, stream>>>(
          Ap, Wv1t, nullptr, nullptr, 0, nullptr, nullptr, nullptr, 0, nullptr, P);
    else
      gemm_k<128, 128, 4, 0, 8192, NE * DH, 2048><<<dim3(NB / 128, DK / 128, 4), 256, 0, stream>>>(
          Ap, Wv1t + (size_t)8192, nullptr, nullptr, 0, nullptr, nullptr, nullptr, 0, nullptr, P);
  }
  cvt_ti_k<<<(NB * DK / 8 + 255) / 256, 256, 0, stream>>>(twin, P, ti);

  // tower
  gemm_k<64, 64, 0, 1, DK, DK, DK><<<dim3(NB / 64, 512 / 64, 1), 256, 0, stream>>>(
      ti, Wt0t, bt0, h1, 512, nullptr, nullptr, nullptr, 0, nullptr, nullptr);
  gemm_k<64, 64, 0, 1, 512, 512, 512><<<dim3(NB / 64, 256 / 64, 1), 256, 0, stream>>>(
      h1, Wt1t, bt1, h2, 256, nullptr, nullptr, nullptr, 0, nullptr, nullptr);
  qfinal_k<<<NB / 4, 256, 0, stream>>>(h2, Wt2, bt2, out);
}

// Round 6
// 709.552 us; speedup vs baseline: 1.1528x; 1.0098x over previous
//
#include <hip/hip_runtime.h>
#include <cstdint>
#include <cstddef>

#define NB   4096
#define OBS  512
#define NACT 64
#define NT   10
#define NE   16
#define DREP 1024
#define DH   1024
#define DK   512
#define SLD  (OBS + NT)    // 522, state row length
#define XK   (OBS + NACT)  // 576

typedef short s8v __attribute__((ext_vector_type(8)));  // 8 bf16 in 4 VGPRs
typedef float f4v __attribute__((ext_vector_type(4)));

__device__ __forceinline__ unsigned short f2bf(float f) {
  union { float f; unsigned int u; } v; v.f = f;
  unsigned int u = v.u;
  unsigned int r = (u + 0x7FFFu + ((u >> 16) & 1u)) >> 16;  // RNE
  return (unsigned short)r;
}
__device__ __forceinline__ float bf2f(unsigned short h) {
  union { unsigned int u; float f; } v; v.u = ((unsigned int)h) << 16;
  return v.f;
}

__device__ __forceinline__ void gload_lds16(const unsigned short* gp, const unsigned short* lp) {
  __builtin_amdgcn_global_load_lds(
      (const __attribute__((address_space(1))) void*)(uintptr_t)gp,
      (__attribute__((address_space(3))) void*)(unsigned int)(uintptr_t)lp,
      16, 0, 0);
}

// ---------------------------------------------------------------------------
// Generic bf16 GEMM: C[M,N] = A[M,K] @ Bt[N,K]^T  (Bt is N-major, K contiguous)
// 3-stage pipelined K-loop, 128x128 tile, 4 waves. Kept for rep-MLP, split-K
// V2 (MODE 3/4) and tower.
// MODE 0: out = bf16(maybe_relu(C + bias[col]))
// MODE 3 (split-K partial write): P[z][row][col]  = C
// MODE 4 (split-K partial add):   P[z][row][col] += C
// ---------------------------------------------------------------------------
template <int BM, int BN, int MODE, int RELU, int LDA, int LDB, int KK>
__global__ void __launch_bounds__(256)
gemm_k(const unsigned short* __restrict__ A,
       const unsigned short* __restrict__ Bt,
       const float* __restrict__ bias,
       unsigned short* __restrict__ outB, int ldo,
       const float* __restrict__ qk1, const int* __restrict__ task,
       float* __restrict__ logits, int eBase,
       const float* __restrict__ attn, float* __restrict__ cio)
{
  constexpr int FM = BM / 32;   // 16x16 frags per wave (M)
  constexpr int FN = BN / 32;
  constexpr int CA = BM / 64;   // 1KB staging chunks per wave (A)
  constexpr int CB = BN / 64;
  constexpr int NTILES = KK / 32;
  static_assert(NTILES >= 3, "pipeline depth");
  constexpr int LPS = CA + CB;           // loads per stage per wave
  static_assert(LPS < 16, "vmcnt immediate fits in low bits");
  constexpr int WAIT_STAGE = 0xF70 | LPS;  // vmcnt(LPS): prev stage done
  constexpr int WAIT_ALL   = 0xF70;        // vmcnt(0): drain (tail only)

  __shared__ __align__(16) unsigned short As[3][BM * 32];
  __shared__ __align__(16) unsigned short Bs[3][BN * 32];

  const int tid  = threadIdx.x;
  const int wave = tid >> 6;
  const int lane = tid & 63;
  const int wm = wave >> 1, wn = wave & 1;

  const int rowBase = blockIdx.x * BM;
  const int colBase = blockIdx.y * BN;

  if (MODE == 3 || MODE == 4) {
    A   += (size_t)blockIdx.z * KK;    // K-chunk
    Bt  += (size_t)blockIdx.z * KK;
    cio += (size_t)blockIdx.z * NB * DK;
  }

  f4v acc[FM][FN];
#pragma unroll
  for (int m = 0; m < FM; ++m)
#pragma unroll
    for (int n = 0; n < FN; ++n) acc[m][n] = f4v{0.f, 0.f, 0.f, 0.f};

  const int sRow = lane >> 2;                                 // row within 16-row chunk
  const int sSw  = ((lane & 3) ^ ((sRow >> 1) & 3)) * 8;      // swizzled global k-offset

  const unsigned short* ag[CA];
  const unsigned short* bg[CB];
#pragma unroll
  for (int j = 0; j < CA; ++j)
    ag[j] = A + (size_t)(rowBase + (wave * CA + j) * 16 + sRow) * LDA + sSw;
#pragma unroll
  for (int j = 0; j < CB; ++j)
    bg[j] = Bt + (size_t)(colBase + (wave * CB + j) * 16 + sRow) * LDB + sSw;

  const int fr   = lane & 15;
  const int koSw = ((lane >> 4) ^ ((fr >> 1) & 3)) * 8;       // swizzled read slot
  const int aOff = (wm * (BM / 2) + fr) * 32 + koSw;
  const int bOff = (wn * (BN / 2) + fr) * 32 + koSw;

  auto stage = [&](int buf) {
#pragma unroll
    for (int j = 0; j < CA; ++j) { gload_lds16(ag[j], &As[buf][(wave * CA + j) * 512]); ag[j] += 32; }
#pragma unroll
    for (int j = 0; j < CB; ++j) { gload_lds16(bg[j], &Bs[buf][(wave * CB + j) * 512]); bg[j] += 32; }
  };

  auto compute = [&](int buf) {
    s8v av[FM], bv[FN];
#pragma unroll
    for (int m = 0; m < FM; ++m)
      av[m] = *reinterpret_cast<const s8v*>(&As[buf][aOff + m * 512]);
#pragma unroll
    for (int n = 0; n < FN; ++n)
      bv[n] = *reinterpret_cast<const s8v*>(&Bs[buf][bOff + n * 512]);
#pragma unroll
    for (int m = 0; m < FM; ++m)
#pragma unroll
      for (int n = 0; n < FN; ++n)
        acc[m][n] = __builtin_amdgcn_mfma_f32_16x16x32_bf16(av[m], bv[n], acc[m][n], 0, 0, 0);
  };

  stage(0);   // tile 0
  stage(1);   // tile 1

  for (int t = 0; t < NTILES; t += 3) {
    // ---- tile t (buf 0) ----
    if (t + 1 < NTILES) __builtin_amdgcn_s_waitcnt(WAIT_STAGE);
    else                __builtin_amdgcn_s_waitcnt(WAIT_ALL);
    __builtin_amdgcn_s_barrier();
    if (t + 2 < NTILES) stage(2);
    compute(0);
    // ---- tile t+1 (buf 1) ----
    if (t + 1 < NTILES) {
      if (t + 2 < NTILES) __builtin_amdgcn_s_waitcnt(WAIT_STAGE);
      else                __builtin_amdgcn_s_waitcnt(WAIT_ALL);
      __builtin_amdgcn_s_barrier();
      if (t + 3 < NTILES) stage(0);
      compute(1);
    }
    // ---- tile t+2 (buf 2) ----
    if (t + 2 < NTILES) {
      if (t + 3 < NTILES) __builtin_amdgcn_s_waitcnt(WAIT_STAGE);
      else                __builtin_amdgcn_s_waitcnt(WAIT_ALL);
      __builtin_amdgcn_s_barrier();
      if (t + 4 < NTILES) stage(1);
      compute(2);
    }
  }

  // ---------------- epilogue ----------------
  const int cr = (lane >> 4) * 4;  // row base within fragment
  const int cc = lane & 15;        // col within fragment

  int gcn[FN];
  float bcol[FN];
#pragma unroll
  for (int n = 0; n < FN; ++n) {
    gcn[n] = colBase + wn * (BN / 2) + n * 16 + cc;
    bcol[n] = (MODE >= 3) ? 0.f : bias[gcn[n]];
  }

  if (MODE == 0) {
#pragma unroll
    for (int m = 0; m < FM; ++m)
#pragma unroll
      for (int r = 0; r < 4; ++r) {
        int gr = rowBase + wm * (BM / 2) + m * 16 + cr + r;
#pragma unroll
        for (int n = 0; n < FN; ++n) {
          float v = acc[m][n][r] + bcol[n];
          if (RELU) v = fmaxf(v, 0.f);
          outB[(size_t)gr * ldo + gcn[n]] = f2bf(v);
        }
      }
  }

  if (MODE == 3 || MODE == 4) {
#pragma unroll
    for (int m = 0; m < FM; ++m)
#pragma unroll
      for (int r = 0; r < 4; ++r) {
        int gr = rowBase + wm * (BM / 2) + m * 16 + cr + r;
#pragma unroll
        for (int n = 0; n < FN; ++n) {
          float v = acc[m][n][r];
          if (MODE == 4) v += cio[(size_t)gr * DK + gcn[n]];
          cio[(size_t)gr * DK + gcn[n]] = v;
        }
      }
  }
}

// ---------------------------------------------------------------------------
// 256x256-tile, BK=64, 8-wave GEMM, v5: REGISTER-SET ROTATION to kill the
// per-wave WAR hazard that pinned R1/R2/R3 at 34-37% MfmaUtil.
// Theory (R5 post-mortem): each phase's ds_reads overwrite the SAME fragment
// VGPRs the just-issued MFMA block is still reading while the matrix pipe
// drains (16 MFMA x ~16 cyc/SIMD).  The read issue stalls behind the drain ->
// phases serialize regardless of barrier placement (why 3 schedules tied).
// Fix: every ds_read targets registers whose last MFMA use is >=2 blocks
// (or 1 block + tile barrier) back:
//   aP/aQ = A-half0, tile-parity sets (used in 1st AND last block of a tile;
//           single set would WAR across the tile boundary)
//   aR    = A-half1 single set (used blocks 2,3; refilled at next block 1)
//   bS    = B-half0 single set (used blocks 1,2; refilled at next block 1)
//   bW    = B-half1 single set (used blocks 3,4; refilled at next block 2)
// Read placement per tile: block1-pre: aX<-A0, bS<-B0, aR<-A1 (16 b128);
// block2-pre: bW<-B1 (8 b128).  24 b128/tile/wave — identical LDS traffic,
// identical addresses, identical accumulation order as R3 (numerics equal).
// Staging/barrier/vmcnt structure = R3 (stage t+1 during t, vmcnt(0)+barrier
// at tile end).  Cost: +48 VGPR of fragments (~176 total) — still 2 w/SIMD.
// MODE 1 (K-pass): v=relu(C+bk0[e,col]); logits[row,e] += v*qk1[e,task,col]
// MODE 2 (V-pass): out = bf16(attn[row,e] * relu(C + bv0[e,col]))
// ---------------------------------------------------------------------------
template <int MODE, int LDA, int LDB, int KK>
__global__ void __launch_bounds__(512)
gemm256_k(const unsigned short* __restrict__ A,
          const unsigned short* __restrict__ Bt,
          const float* __restrict__ bias,
          unsigned short* __restrict__ outB, int ldo,
          const float* __restrict__ qk1, const int* __restrict__ task,
          float* __restrict__ logits, int eBase,
          const float* __restrict__ attn)
{
  constexpr int NTK = KK / 64;
  static_assert(NTK >= 4 && (NTK & 1) == 0, "pipeline depth");

  __shared__ __align__(16) unsigned short As[2][16384];  // [buf][row*64 + swz k]
  __shared__ __align__(16) unsigned short Bs[2][16384];

  const int tid  = threadIdx.x;
  const int wave = tid >> 6;
  const int lane = tid & 63;
  const int l3 = lane >> 3, l7 = lane & 7, l4 = lane >> 4;

  // ---- XCD-bijective block swizzle (requires nwg % 8 == 0; holds here) ----
  const int gx = gridDim.x, gy = gridDim.y;
  int flat = blockIdx.x + gx * (blockIdx.y + gy * blockIdx.z);
  const int nwg = gx * gy * gridDim.z;
  flat = (flat & 7) * (nwg >> 3) + (flat >> 3);
  const int bx = flat % gx; flat /= gx;
  const int by = flat % gy;
  const int bz = flat / gy;

  const int rowBase = bx * 256;
  const int colBase = by * 256;

  int eg = 0;
  if (MODE == 1) {
    eg = bz;
    Bt   += (size_t)eg * ((size_t)DREP * DH);
    bias += eg * DH;
    qk1  += (size_t)eg * (NT * DH);
  }
  if (MODE == 2) {
    eg = eBase + bz;
    Bt   += (size_t)eg * ((size_t)DREP * DH);
    bias += eg * DH;
    outB += (size_t)bz * DH;   // local slab in Ap
  }

  f4v acc[2][2][2][4];   // [qm][qn][f][fc]
#pragma unroll
  for (int i0 = 0; i0 < 2; ++i0)
#pragma unroll
    for (int i1 = 0; i1 < 2; ++i1)
#pragma unroll
      for (int i2 = 0; i2 < 2; ++i2)
#pragma unroll
        for (int i3 = 0; i3 < 4; ++i3)
          acc[i0][i1][i2][i3] = f4v{0.f, 0.f, 0.f, 0.f};

  // ---- persistent staging pointers: [half][j], bump += 64 shorts per tile.
  const unsigned short* pA[2][2];
  const unsigned short* pB[2][2];
#pragma unroll
  for (int h = 0; h < 2; ++h)
#pragma unroll
    for (int j = 0; j < 2; ++j) {
      const int r  = h * 128 + j * 64 + wave * 8 + l3;
      const int ks = (l7 ^ l3) * 8;
      pA[h][j] = A  + (size_t)(rowBase + r) * LDA + ks;
      pB[h][j] = Bt + (size_t)(colBase + r) * LDB + ks;
    }

  auto stageA = [&](int buf, int h) {
#pragma unroll
    for (int j = 0; j < 2; ++j) {
      gload_lds16(pA[h][j], &As[buf][h * 8192 + j * 4096 + wave * 512]);
      pA[h][j] += 64;
    }
  };
  auto stageB = [&](int buf, int h) {
#pragma unroll
    for (int j = 0; j < 2; ++j) {
      gload_lds16(pB[h][j], &Bs[buf][h * 8192 + j * 4096 + wave * 512]);
      pB[h][j] += 64;
    }
  };

  // ---- LDS -> fragment reads (swizzle-aware, addresses identical to R3) ----
  const int cOff0 = (l4 ^ l7) * 8;
  const int cOff1 = ((4 + l4) ^ l7) * 8;
  const int aRowOff = ((wave & 3) * 32 + (lane & 15)) * 64;
  const int bColOff = ((wave >> 2) * 64 + (lane & 15)) * 64;

  // Fragment register sets (WAR-free rotation):
  s8v aP[2][2], aQ[2][2], aR[2][2];   // A0-even, A0-odd, A1-shared
  s8v bS[4][2], bW[4][2];             // B0-shared, B1-shared

  auto readAh = [&](int buf, int h, s8v (&av)[2][2]) {
#pragma unroll
    for (int f = 0; f < 2; ++f) {
      const unsigned short* p = &As[buf][h * 8192 + aRowOff + f * 1024];
      av[f][0] = *reinterpret_cast<const s8v*>(p + cOff0);
      av[f][1] = *reinterpret_cast<const s8v*>(p + cOff1);
    }
  };
  auto readB = [&](int buf, int qn, s8v (&bv)[4][2]) {
#pragma unroll
    for (int fc = 0; fc < 4; ++fc) {
      const unsigned short* p = &Bs[buf][qn * 8192 + bColOff + fc * 1024];
      bv[fc][0] = *reinterpret_cast<const s8v*>(p + cOff0);
      bv[fc][1] = *reinterpret_cast<const s8v*>(p + cOff1);
    }
  };

#define MFMA_BLK(QM, QN, AV, BV)                                              \
  do {                                                                        \
    __builtin_amdgcn_s_setprio(1);                                            \
    _Pragma("unroll") for (int ks_ = 0; ks_ < 2; ++ks_)                       \
      _Pragma("unroll") for (int f_ = 0; f_ < 2; ++f_)                        \
        _Pragma("unroll") for (int fc_ = 0; fc_ < 4; ++fc_)                   \
          acc[QM][QN][f_][fc_] = __builtin_amdgcn_mfma_f32_16x16x32_bf16(     \
              AV[f_][ks_], BV[fc_][ks_], acc[QM][QN][f_][fc_], 0, 0, 0);      \
    __builtin_amdgcn_s_setprio(0);                                            \
  } while (0)

  // ---- prologue: stage tile0, drain, barrier ----
  stageA(0, 0); stageB(0, 0); stageA(0, 1); stageB(0, 1);
  __builtin_amdgcn_s_waitcnt(0xF70);
  __builtin_amdgcn_s_barrier();

  for (int t = 0; t < NTK; t += 2) {
    // ======== even tile (buf 0), sets aP ========
    // blk1-pre: all A reads + B0; stage A(t+1).  WAR gaps: aP 4 blks back,
    // bS 2 blks, aR 1 blk + barrier — all >= drain distance.
    readAh(0, 0, aP); readB(0, 0, bS); readAh(0, 1, aR);
    stageA(1, 0); stageA(1, 1);                 // t+1 < NTK always (t even)
    MFMA_BLK(0, 0, aP, bS);
    // blk2-pre: B1; stage B(t+1).  bW last used 1 blk + barrier back.
    readB(0, 1, bW);
    stageB(1, 0); stageB(1, 1);
    MFMA_BLK(1, 0, aR, bS);
    MFMA_BLK(1, 1, aR, bW);
    MFMA_BLK(0, 1, aP, bW);
    __builtin_amdgcn_s_waitcnt(0xF70);          // tile t+1 fully resident
    __builtin_amdgcn_s_barrier();
    // ======== odd tile (buf 1), sets aQ ========
    {
      const bool st = (t + 2) < NTK;
      readAh(1, 0, aQ); readB(1, 0, bS); readAh(1, 1, aR);
      if (st) { stageA(0, 0); stageA(0, 1); }
      MFMA_BLK(0, 0, aQ, bS);
      readB(1, 1, bW);
      if (st) { stageB(0, 0); stageB(0, 1); }
      MFMA_BLK(1, 0, aR, bS);
      MFMA_BLK(1, 1, aR, bW);
      MFMA_BLK(0, 1, aQ, bW);
      if (st) {
        __builtin_amdgcn_s_waitcnt(0xF70);
        __builtin_amdgcn_s_barrier();
      }
    }
  }
#undef MFMA_BLK

  // ---------------- epilogue ----------------
  const int cr = l4 * 4;
  const int cc = lane & 15;

  int gcn[2][4];
  float bcol[2][4];
#pragma unroll
  for (int qn = 0; qn < 2; ++qn)
#pragma unroll
    for (int fc = 0; fc < 4; ++fc) {
      gcn[qn][fc]  = colBase + qn * 128 + (wave >> 2) * 64 + fc * 16 + cc;
      bcol[qn][fc] = bias[gcn[qn][fc]];
    }

  if (MODE == 1) {
#pragma unroll
    for (int qm = 0; qm < 2; ++qm)
#pragma unroll
      for (int f = 0; f < 2; ++f)
#pragma unroll
        for (int r = 0; r < 4; ++r) {
          const int gr = rowBase + qm * 128 + (wave & 3) * 32 + f * 16 + cr + r;
          const float* qrow = qk1 + (size_t)task[gr] * DH;
          float s = 0.f;
#pragma unroll
          for (int qn = 0; qn < 2; ++qn)
#pragma unroll
            for (int fc = 0; fc < 4; ++fc) {
              float v = fmaxf(acc[qm][qn][f][fc][r] + bcol[qn][fc], 0.f);
              s += v * qrow[gcn[qn][fc]];
            }
#pragma unroll
          for (int off = 1; off < 16; off <<= 1) s += __shfl_xor(s, off, 64);
          if (cc == 0) atomicAdd(&logits[gr * NE + eg], s);
        }
  }

  if (MODE == 2) {
#pragma unroll
    for (int qm = 0; qm < 2; ++qm)
#pragma unroll
      for (int f = 0; f < 2; ++f)
#pragma unroll
        for (int r = 0; r < 4; ++r) {
          const int gr = rowBase + qm * 128 + (wave & 3) * 32 + f * 16 + cr + r;
          const float aw = attn[gr * NE + eg];
#pragma unroll
          for (int qn = 0; qn < 2; ++qn)
#pragma unroll
            for (int fc = 0; fc < 4; ++fc) {
              float v = fmaxf(acc[qm][qn][f][fc][r] + bcol[qn][fc], 0.f) * aw;
              outB[(size_t)gr * ldo + gcn[qn][fc]] = f2bf(v);
            }
        }
  }
}

// ---------------------------------------------------------------------------
// front_k: fused {task argmax | buildx bf16 pack | qb dot | Qt tanh}.
// ---------------------------------------------------------------------------
__global__ void __launch_bounds__(256)
front_k(const float* __restrict__ state, const float* __restrict__ act,
        const float* __restrict__ emb, const float* __restrict__ bk1,
        unsigned short* __restrict__ x, int* __restrict__ task,
        float* __restrict__ Qt, float* __restrict__ qb)
{
  const int blk = blockIdx.x, tid = threadIdx.x;
  if (blk < 16) {                      // ---- task argmax ----
    int b = blk * 256 + tid;
    const float* p = state + (size_t)b * SLD + OBS;
    float best = p[0]; int bi = 0;
    for (int j = 1; j < NT; ++j) { float v = p[j]; if (v > best) { best = v; bi = j; } }
    task[b] = bi;
  } else if (blk < 16 + 1152) {        // ---- buildx, vectorized ----
    int idx8 = (blk - 16) * 256 + tid;            // < 4096*72
    int b = idx8 / 72, c8 = idx8 - b * 72, j = c8 * 8;
    float v[8];
    if (j < OBS) {
      const float* s = state + (size_t)b * SLD + j;
#pragma unroll
      for (int q = 0; q < 8; ++q) v[q] = s[q];
    } else {
      const float* a = act + (size_t)b * NACT + (j - OBS);
#pragma unroll
      for (int q = 0; q < 8; ++q) v[q] = a[q];
    }
    unsigned short v8[8];
#pragma unroll
    for (int q = 0; q < 8; ++q) v8[q] = f2bf(v[q]);
    *reinterpret_cast<s8v*>(x + (size_t)b * XK + j) = *reinterpret_cast<const s8v*>(v8);
  } else if (blk < 16 + 1152 + 40) {   // ---- qb[e,t] = tanh(emb[t]).bk1[e] ----
    int w = (blk - 1168) * 4 + (tid >> 6), lane = tid & 63;   // w < 160
    int e = w / NT, t = w - e * NT;
    const float* ep = emb + t * DK + lane * 8;
    const float* bp = bk1 + e * DK + lane * 8;
    float s = 0.f;
#pragma unroll
    for (int q = 0; q < 8; ++q) s += tanhf(ep[q]) * bp[q];
    for (int off = 1; off < 64; off <<= 1) s += __shfl_xor(s, off, 64);
    if (lane == 0) qb[e * NT + t] = s;
  } else {                             // ---- Qt = tanh(emb) ----
    int idx = (blk - 1208) * 256 + tid;           // < NT*DK = 5120 exactly
    Qt[idx] = tanhf(emb[idx]);
  }
}

// wave per (e,h): qk1[e,t,h] = sum_k Wk1[e,h,k] * Qt[t,k]
__global__ void qk1_k(const float* __restrict__ Wk1, const float* __restrict__ Qt,
                      float* __restrict__ qk1) {
  int w = (blockIdx.x * blockDim.x + threadIdx.x) >> 6;
  int lane = threadIdx.x & 63;
  if (w >= NE * DH) return;
  int e = w >> 10, h = w & (DH - 1);
  const float* wrow = Wk1 + ((size_t)e * DH + h) * DK + lane * 8;
  float wv[8];
#pragma unroll
  for (int j = 0; j < 8; ++j) wv[j] = wrow[j];
#pragma unroll
  for (int t = 0; t < NT; ++t) {
    const float* qrow = Qt + t * DK + lane * 8;
    float s = 0.f;
#pragma unroll
    for (int j = 0; j < 8; ++j) s += wv[j] * qrow[j];
#pragma unroll
    for (int off = 1; off < 64; off <<= 1) s += __shfl_xor(s, off, 64);
    if (lane == 0) qk1[((size_t)e * NT + t) * DH + h] = s;
  }
}

// ---------------------------------------------------------------------------
// convT_all_k: ALL 7 weight transposes (fp32 -> bf16, [K][N] -> [N][K]) in
// ONE launch, job selected by flat blockIdx range.
// ---------------------------------------------------------------------------
__global__ void __launch_bounds__(256)
convT_all_k(const float* __restrict__ W0,  unsigned short* __restrict__ dW0,
            const float* __restrict__ W1,  unsigned short* __restrict__ dW1,
            const float* __restrict__ Wk0, unsigned short* __restrict__ dWk0,
            const float* __restrict__ Wv0, unsigned short* __restrict__ dWv0,
            const float* __restrict__ Wv1, unsigned short* __restrict__ dWv1,
            const float* __restrict__ Wt0, unsigned short* __restrict__ dWt0,
            const float* __restrict__ Wt1, unsigned short* __restrict__ dWt1)
{
  int id = blockIdx.x;
  const float* src; unsigned short* dst;
  int N, dLd, nx, tpe; long sBS, dBS;
  if (id < 144)        {            src = W0;  dst = dW0;  N = 1024; sBS = 0; dBS = 0; dLd = 576;   nx = 16; tpe = 144; }
  else if (id < 400)   { id -= 144; src = W1;  dst = dW1;  N = 1024; sBS = 0; dBS = 0; dLd = 1024;  nx = 16; tpe = 256; }
  else if (id < 4496)  { id -= 400; src = Wk0; dst = dWk0; N = 1024; sBS = (long)DREP * DH; dBS = (long)DREP * DH; dLd = 1024; nx = 16; tpe = 256; }
  else if (id < 8592)  { id -= 4496; src = Wv0; dst = dWv0; N = 1024; sBS = (long)DREP * DH; dBS = (long)DREP * DH; dLd = 1024; nx = 16; tpe = 256; }
  else if (id < 10640) { id -= 8592; src = Wv1; dst = dWv1; N = 512;  sBS = (long)DH * DK; dBS = 1024; dLd = NE * DH; nx = 8; tpe = 128; }
  else if (id < 10704) { id -= 10640; src = Wt0; dst = dWt0; N = 512; sBS = 0; dBS = 0; dLd = 512; nx = 8; tpe = 64; }
  else                 { id -= 10704; src = Wt1; dst = dWt1; N = 256; sBS = 0; dBS = 0; dLd = 512; nx = 4; tpe = 32; }
  const int e  = id / tpe;
  const int r  = id - e * tpe;
  const int n0 = (r % nx) * 64, k0 = (r / nx) * 64;

  __shared__ float tile[64][65];
  src += (size_t)e * sBS + (size_t)k0 * N + n0;
  dst += (size_t)e * dBS + (size_t)n0 * dLd + k0;
  int t = threadIdx.x;
  int c4 = t & 15, kr = t >> 4;            // 16 float4-cols x 16 rows per pass
#pragma unroll
  for (int i = 0; i < 4; ++i) {
    float4 v = *(const float4*)(src + (size_t)(kr + i * 16) * N + c4 * 4);
    tile[kr + i * 16][c4 * 4 + 0] = v.x;
    tile[kr + i * 16][c4 * 4 + 1] = v.y;
    tile[kr + i * 16][c4 * 4 + 2] = v.z;
    tile[kr + i * 16][c4 * 4 + 3] = v.w;
  }
  __syncthreads();
  int sub = t & 7, nl = t >> 3;            // 8 k-chunks x 32 n per pass
#pragma unroll
  for (int pass = 0; pass < 2; ++pass) {
    int n = nl + pass * 32;
    unsigned short v8[8];
#pragma unroll
    for (int j = 0; j < 8; ++j) v8[j] = f2bf(tile[sub * 8 + j][n]);
    *reinterpret_cast<s8v*>(dst + (size_t)n * dLd + sub * 8) =
        *reinterpret_cast<const s8v*>(v8);
  }
}

// ---------------------------------------------------------------------------
// attn_k: fused softmax + expert-loss + towerbias.
// ---------------------------------------------------------------------------
__global__ void __launch_bounds__(256)
attn_k(const float* __restrict__ logits, const float* __restrict__ qb,
       const int* __restrict__ task, const float* __restrict__ bv1,
       float* __restrict__ attn, float* __restrict__ twin,
       float* __restrict__ lossOut)
{
  __shared__ float aL[16][16];
  __shared__ float lred[4];
  const int tid = threadIdx.x;
  const int rr = tid >> 4, e = tid & 15;
  const int b = blockIdx.x * 16 + rr;
  const int t = task[b];
  float l = logits[b * NE + e] + qb[e * NT + t];
  float mx = l;
#pragma unroll
  for (int off = 1; off < 16; off <<= 1) mx = fmaxf(mx, __shfl_xor(mx, off, 64));
  float ex = expf(l - mx);
  float s = ex;
#pragma unroll
  for (int off = 1; off < 16; off <<= 1) s += __shfl_xor(s, off, 64);
  float a = ex / s;
  attn[b * NE + e] = a;
  aL[rr][e] = a;
  float loss = fminf(fmaxf(logf(a + 1e-10f), -6.f), 0.f);
#pragma unroll
  for (int off = 1; off < 64; off <<= 1) loss += __shfl_xor(loss, off, 64);
  if ((tid & 63) == 0) lred[tid >> 6] = loss;
  __syncthreads();
  if (tid == 0)
    atomicAdd(lossOut, (lred[0] + lred[1] + lred[2] + lred[3]) * (-0.3f / NB));
  // ---- towerbias: twin[b, :] = sum_e attn[b,e] * bv1[e, :] ----
  float av[NE];
#pragma unroll
  for (int q = 0; q < NE; ++q) av[q] = aL[rr][q];
  float* tw = twin + (size_t)b * DK;
  for (int j = 0; j < 32; ++j) {
    int k = e + j * 16;
    float sv = 0.f;
#pragma unroll
    for (int q = 0; q < NE; ++q) sv += av[q] * bv1[q * DK + k];
    tw[k] = sv;
  }
}

// ti = bf16(twin + P0 + P1 + P2 + P3), 8 elems/thread
__global__ void cvt_ti_k(const float* __restrict__ twin, const float* __restrict__ P,
                         unsigned short* __restrict__ ti) {
  int idx = (blockIdx.x * blockDim.x + threadIdx.x) * 8;
  if (idx >= NB * DK) return;
  float v[8];
#pragma unroll
  for (int j = 0; j < 8; ++j) v[j] = twin[idx + j];
#pragma unroll
  for (int c = 0; c < 4; ++c) {
    const float* p = P + (size_t)c * NB * DK + idx;
#pragma unroll
    for (int j = 0; j < 8; ++j) v[j] += p[j];
  }
  unsigned short v8[8];
#pragma unroll
  for (int j = 0; j < 8; ++j) v8[j] = f2bf(v[j]);
  *reinterpret_cast<s8v*>(ti + idx) = *reinterpret_cast<const s8v*>(v8);
}

// wave per row: q[b] = h2[b,:] . Wt2 + bt2
__global__ void qfinal_k(const unsigned short* __restrict__ h2, const float* __restrict__ Wt2,
                         const float* __restrict__ bt2, float* __restrict__ out) {
  int w = (blockIdx.x * blockDim.x + threadIdx.x) >> 6;
  int lane = threadIdx.x & 63;
  if (w >= NB) return;
  float s = 0.f;
#pragma unroll
  for (int j = 0; j < 4; ++j) {
    int k = lane * 4 + j;
    s += bf2f(h2[(size_t)w * 256 + k]) * Wt2[k];
  }
  for (int off = 1; off < 64; off <<= 1) s += __shfl_xor(s, off, 64);
  if (lane == 0) out[w] = s + bt2[0];
}

// ---------------------------------------------------------------------------
extern "C" void kernel_launch(void* const* d_in, const int* in_sizes, int n_in,
                              void* d_out, int out_size, void* d_ws, size_t ws_size,
                              hipStream_t stream) {
  const float* state  = (const float*)d_in[0];
  const float* act    = (const float*)d_in[1];
  const float* rep_W0 = (const float*)d_in[2];
  const float* rep_b0 = (const float*)d_in[3];
  const float* rep_W1 = (const float*)d_in[4];
  const float* rep_b1 = (const float*)d_in[5];
  const float* emb    = (const float*)d_in[6];
  const float* Wk0    = (const float*)d_in[7];
  const float* bk0    = (const float*)d_in[8];
  const float* Wk1    = (const float*)d_in[9];
  const float* bk1    = (const float*)d_in[10];
  const float* Wv0    = (const float*)d_in[11];
  const float* bv0    = (const float*)d_in[12];
  const float* Wv1    = (const float*)d_in[13];
  const float* bv1    = (const float*)d_in[14];
  const float* Wt0    = (const float*)d_in[15];
  const float* bt0    = (const float*)d_in[16];
  const float* Wt1    = (const float*)d_in[17];
  const float* bt1    = (const float*)d_in[18];
  const float* Wt2    = (const float*)d_in[19];
  const float* bt2    = (const float*)d_in[20];
  float* out = (float*)d_out;

  char* wsb = (char*)d_ws;
  size_t off = 0;
  auto alloc = [&](size_t bytes) -> void* {
    void* p = wsb + off;
    off += (bytes + 255) & ~(size_t)255;
    return p;
  };
  unsigned short* Ap    = (unsigned short*)alloc((size_t)NB * 8192 * 2);       // scaled hv, 8 experts
  unsigned short* Wk0t  = (unsigned short*)alloc((size_t)NE * DREP * DH * 2);
  unsigned short* Wv0t  = (unsigned short*)alloc((size_t)NE * DREP * DH * 2);
  unsigned short* Wv1t  = (unsigned short*)alloc((size_t)DK * (NE * DH) * 2);  // [n][e*1024+h]
  float*          P     = (float*)alloc((size_t)4 * NB * DK * 4);              // split-K partials
  unsigned short* h0    = (unsigned short*)alloc((size_t)NB * DREP * 2);
  unsigned short* rep   = (unsigned short*)alloc((size_t)NB * DREP * 2);
  float*          twin  = (float*)alloc((size_t)NB * DK * 4);
  unsigned short* xbuf  = (unsigned short*)alloc((size_t)NB * XK * 2);
  unsigned short* ti    = (unsigned short*)alloc((size_t)NB * DK * 2);
  unsigned short* h1    = (unsigned short*)alloc((size_t)NB * 512 * 2);
  unsigned short* h2    = (unsigned short*)alloc((size_t)NB * 256 * 2);
  unsigned short* rW1t  = (unsigned short*)alloc((size_t)DREP * DREP * 2);
  unsigned short* rW0t  = (unsigned short*)alloc((size_t)DREP * XK * 2);
  float*          qk1   = (float*)alloc((size_t)NE * NT * DH * 4);
  unsigned short* Wt0t  = (unsigned short*)alloc((size_t)512 * 512 * 2);
  unsigned short* Wt1t  = (unsigned short*)alloc((size_t)256 * 512 * 2);
  float*          logits= (float*)alloc((size_t)NB * NE * 4);
  float*          attn  = (float*)alloc((size_t)NB * NE * 4);
  float*          Qt    = (float*)alloc((size_t)NT * DK * 4);
  int*            task  = (int*)alloc((size_t)NB * 4);
  float*          qb    = (float*)alloc((size_t)NE * NT * 4);

  hipMemsetAsync(logits, 0, (size_t)NB * NE * 4, stream);
  hipMemsetAsync(out + NB, 0, sizeof(float), stream);

  // fused front: task | buildx | qb | Qt   (16 + 1152 + 40 + 20 blocks)
  front_k<<<1228, 256, 0, stream>>>(state, act, emb, bk1, xbuf, task, Qt, qb);
  qk1_k<<<NE * DH / 4, 256, 0, stream>>>(Wk1, Qt, qk1);

  // all 7 weight transposes in one launch (10736 blocks)
  convT_all_k<<<10736, 256, 0, stream>>>(rep_W0, rW0t, rep_W1, rW1t,
                                         Wk0, Wk0t, Wv0, Wv0t, Wv1, Wv1t,
                                         Wt0, Wt0t, Wt1, Wt1t);

  // rep MLP (128-tile kernel)
  gemm_k<128, 128, 0, 1, XK, XK, XK><<<dim3(NB / 128, DREP / 128, 1), 256, 0, stream>>>(
      xbuf, rW0t, rep_b0, h0, DREP, nullptr, nullptr, nullptr, 0, nullptr, nullptr);
  gemm_k<128, 128, 0, 0, DREP, DREP, DREP><<<dim3(NB / 128, DREP / 128, 1), 256, 0, stream>>>(
      h0, rW1t, rep_b1, rep, DREP, nullptr, nullptr, nullptr, 0, nullptr, nullptr);

  // K-pass: hk fused into logits (256-tile kernel)
  gemm256_k<1, DREP, DREP, DREP><<<dim3(NB / 256, DH / 256, NE), 512, 0, stream>>>(
      rep, Wk0t, bk0, nullptr, 0, qk1, task, logits, 0, nullptr);

  // fused softmax + loss + towerbias
  attn_k<<<NB / 16, 256, 0, stream>>>(logits, qb, task, bv1, attn, twin, out + NB);

  // V-pass (256-tile) + split-K accumulate into per-chunk partials
  for (int g = 0; g < 2; ++g) {
    gemm256_k<2, DREP, DREP, DREP><<<dim3(NB / 256, DH / 256, 8), 512, 0, stream>>>(
        rep, Wv0t, bv0, Ap, 8192, nullptr, nullptr, nullptr, g * 8, attn);
    if (g == 0)
      gemm_k<128, 128, 3, 0, 8192, NE * DH, 2048><<<dim3(NB / 128, DK / 128, 4), 256, 0, stream>>>(
          Ap, Wv1t, nullptr, nullptr, 0, nullptr, nullptr, nullptr, 0, nullptr, P);
    else
      gemm_k<128, 128, 4, 0, 8192, NE * DH, 2048><<<dim3(NB / 128, DK / 128, 4), 256, 0, stream>>>(
          Ap, Wv1t + (size_t)8192, nullptr, nullptr, 0, nullptr, nullptr, nullptr, 0, nullptr, P);
  }
  cvt_ti_k<<<(NB * DK / 8 + 255) / 256, 256, 0, stream>>>(twin, P, ti);

  // tower
  gemm_k<64, 64, 0, 1, DK, DK, DK><<<dim3(NB / 64, 512 / 64, 1), 256, 0, stream>>>(
      ti, Wt0t, bt0, h1, 512, nullptr, nullptr, nullptr, 0, nullptr, nullptr);
  gemm_k<64, 64, 0, 1, 512, 512, 512><<<dim3(NB / 64, 256 / 64, 1), 256, 0, stream>>>(
      h1, Wt1t, bt1, h2, 256, nullptr, nullptr, nullptr, 0, nullptr, nullptr);
  qfinal_k<<<NB / 4, 256, 0, stream>>>(h2, Wt2, bt2, out);
}